// Round 4
// baseline (508.971 us; speedup 1.0000x reference)
//
#include <hip/hip_runtime.h>

// CrossAttention: out = softmax((S2 Wq)(S1 Wk)^T) (S1 Wv) Wo + bo
// Refactored: Wvo = Wv@Wo;  V'' = S1@Wvo + bo;  out = softmax(QK^T) @ V''
// R10: R9's counted-vmcnt double-buffer pipeline kept verbatim; QK^T wave
// tiles squared from 16x128 to 32x64 (8 waves = 4 row-groups x 2 key-groups):
// frag reads/chunk drop 36->24 per wave (K-chunk re-read redundancy 8x->2x on
// the key axis), sacc stays 32 f32 (register-neutral vs R9 -- R7 proved the
// 256-reg cap is fatal). Softmax adds a pairwise cross-wave combine via small
// LDS partials (+1 barrier/kt). Also: Q/K/V projection GEMMs fused into one
// launch (k_proj3) -- fewer launch gaps, tails overlap, S1h L2 reuse.

typedef _Float16 h_t;
typedef _Float16 h8 __attribute__((ext_vector_type(8)));
typedef _Float16 h4 __attribute__((ext_vector_type(4)));
typedef float f4 __attribute__((ext_vector_type(4)));

#define MFMA16(a, b, c) __builtin_amdgcn_mfma_f32_16x16x32_f16(a, b, c, 0, 0, 0)

typedef const __attribute__((address_space(1))) void* gas_t;
typedef __attribute__((address_space(3))) void* las_t;

__device__ __forceinline__ void gl2lds16(const void* g, void* l) {
    __builtin_amdgcn_global_load_lds((gas_t)g, (las_t)l, 16, 0, 0);
}

// ---------------- merged cast fp32 -> fp16: S1, S2, Wv ----------------
__global__ __launch_bounds__(256) void k_cast3(const float* __restrict__ S1,
                                               const float* __restrict__ S2,
                                               const float* __restrict__ Wv,
                                               h_t* __restrict__ S1h,
                                               h_t* __restrict__ S2h,
                                               h_t* __restrict__ Wvh) {
    long i = (long)blockIdx.x * 256 + threadIdx.x;  // f4 index
    const long n = 2097152;                          // S1/S2 f4 count
    const float* src;
    h_t* dst;
    long off;
    if (i < n) { src = S1; dst = S1h; off = i; }
    else if (i < 2 * n) { src = S2; dst = S2h; off = i - n; }
    else { src = Wv; dst = Wvh; off = i - 2 * n; }
    float4 v = *((const float4*)src + off);
    h4 h = {(h_t)v.x, (h_t)v.y, (h_t)v.z, (h_t)v.w};
    *((h4*)dst + off) = h;
}

// ---------------- merged transpose+cast: Wq, Wk, Wo -> [N][K] f16 ----------------
__global__ __launch_bounds__(256) void k_transpose3(const float* __restrict__ Wq,
                                                    const float* __restrict__ Wk,
                                                    const float* __restrict__ Wo,
                                                    h_t* __restrict__ Wqt,
                                                    h_t* __restrict__ Wkt,
                                                    h_t* __restrict__ Wot) {
    const float* in;
    h_t* out;
    int K, N;
    if (blockIdx.z == 0) { in = Wq; out = Wqt; K = 512; N = 1024; }
    else if (blockIdx.z == 1) { in = Wk; out = Wkt; K = 512; N = 1024; }
    else { in = Wo; out = Wot; K = 1024; N = 512; }
    int kb = blockIdx.y * 32, nb = blockIdx.x * 32;
    if (kb >= K || nb >= N) return;
    __shared__ float tile[32][33];
    int x = threadIdx.x & 31, y = threadIdx.x >> 5;
#pragma unroll
    for (int j = 0; j < 4; j++)
        tile[y + j * 8][x] = in[(size_t)(kb + y + j * 8) * N + nb + x];
    __syncthreads();
#pragma unroll
    for (int j = 0; j < 4; j++)
        out[(size_t)(nb + y + j * 8) * K + kb + x] = (h_t)tile[x][y + j * 8];
}

// ---------------- m97-style NT GEMM: C[M][N] f16 = A[M][K] x Bt[N][K]^T ------------
__global__ __launch_bounds__(256) void k_gemm(const h_t* __restrict__ A,
                                              const h_t* __restrict__ Bt,
                                              h_t* __restrict__ C,
                                              int M, int N, int K) {
    __shared__ h_t As[128 * 64];
    __shared__ h_t Bs[128 * 64];
    int t = threadIdx.x, w = t >> 6, lane = t & 63;
    int q16 = lane >> 4, l16 = lane & 15;
    size_t m0 = (size_t)blockIdx.x * 128, n0 = (size_t)blockIdx.y * 128;
    int wr = (w >> 1) * 64, wc = (w & 1) * 64;
    f4 acc[4][4] = {};

    for (int k0 = 0; k0 < K; k0 += 64) {
#pragma unroll
        for (int j = 0; j < 4; j++) {
            int q = w * 4 + j;
            int row = q * 8 + (lane >> 3);
            int ks = (((lane & 7) ^ (row & 7)) << 3);
            gl2lds16(A + (m0 + row) * K + k0 + ks, &As[q * 512]);
            gl2lds16(Bt + (n0 + row) * K + k0 + ks, &Bs[q * 512]);
        }
        __syncthreads();
#pragma unroll
        for (int ks = 0; ks < 2; ks++) {
            h8 av[4], bv[4];
#pragma unroll
            for (int i = 0; i < 4; i++) {
                int row = wr + i * 16 + l16;
                int ch = ks * 4 + q16;
                av[i] = *(const h8*)&As[row * 64 + ((ch ^ (row & 7)) << 3)];
            }
#pragma unroll
            for (int j = 0; j < 4; j++) {
                int row = wc + j * 16 + l16;
                int ch = ks * 4 + q16;
                bv[j] = *(const h8*)&Bs[row * 64 + ((ch ^ (row & 7)) << 3)];
            }
#pragma unroll
            for (int i = 0; i < 4; i++)
#pragma unroll
                for (int j = 0; j < 4; j++)
                    acc[i][j] = MFMA16(av[i], bv[j], acc[i][j]);
        }
        __syncthreads();
    }
#pragma unroll
    for (int i = 0; i < 4; i++) {
        size_t r0 = m0 + wr + i * 16 + q16 * 4;
#pragma unroll
        for (int j = 0; j < 4; j++) {
            size_t c = n0 + wc + j * 16 + l16;
#pragma unroll
            for (int r = 0; r < 4; r++)
                C[(r0 + r) * N + c] = (h_t)acc[i][j][r];
        }
    }
}

// ---------------- fused Q/K/V'' projections (one launch, 2560 blocks) -------------
// blocks 0..1023: Qh = S2h x Wqt; 1024..2047: Kh = S1h x Wkt;
// 2048..2559: Vt = (S1h x Wvot + bo) stored transposed [b][d][n].
__global__ __launch_bounds__(256) void k_proj3(const h_t* __restrict__ S2h,
                                               const h_t* __restrict__ S1h,
                                               const h_t* __restrict__ Wqt,
                                               const h_t* __restrict__ Wkt,
                                               const h_t* __restrict__ Wvot,
                                               const float* __restrict__ bo,
                                               h_t* __restrict__ Qh,
                                               h_t* __restrict__ Kh,
                                               h_t* __restrict__ Vt) {
    __shared__ h_t As[128 * 64];
    __shared__ h_t Bs[128 * 64];
    int t = threadIdx.x, w = t >> 6, lane = t & 63;
    int q16 = lane >> 4, l16 = lane & 15;
    int id = blockIdx.x;
    const h_t* A;
    const h_t* Bt;
    int N, mode;
    size_t m0, n0;
    if (id < 1024) {
        mode = 0; A = S2h; Bt = Wqt; N = 1024;
        m0 = (size_t)(id >> 3) * 128; n0 = (size_t)(id & 7) * 128;
    } else if (id < 2048) {
        mode = 1; A = S1h; Bt = Wkt; N = 1024;
        id -= 1024; m0 = (size_t)(id >> 3) * 128; n0 = (size_t)(id & 7) * 128;
    } else {
        mode = 2; A = S1h; Bt = Wvot; N = 512;
        id -= 2048; m0 = (size_t)(id >> 2) * 128; n0 = (size_t)(id & 3) * 128;
    }
    const int K = 512;
    int wr = (w >> 1) * 64, wc = (w & 1) * 64;
    f4 acc[4][4] = {};

    for (int k0 = 0; k0 < K; k0 += 64) {
#pragma unroll
        for (int j = 0; j < 4; j++) {
            int q = w * 4 + j;
            int row = q * 8 + (lane >> 3);
            int ks = (((lane & 7) ^ (row & 7)) << 3);
            gl2lds16(A + (m0 + row) * K + k0 + ks, &As[q * 512]);
            gl2lds16(Bt + (n0 + row) * K + k0 + ks, &Bs[q * 512]);
        }
        __syncthreads();
#pragma unroll
        for (int ks = 0; ks < 2; ks++) {
            h8 av[4], bv[4];
#pragma unroll
            for (int i = 0; i < 4; i++) {
                int row = wr + i * 16 + l16;
                int ch = ks * 4 + q16;
                av[i] = *(const h8*)&As[row * 64 + ((ch ^ (row & 7)) << 3)];
            }
#pragma unroll
            for (int j = 0; j < 4; j++) {
                int row = wc + j * 16 + l16;
                int ch = ks * 4 + q16;
                bv[j] = *(const h8*)&Bs[row * 64 + ((ch ^ (row & 7)) << 3)];
            }
#pragma unroll
            for (int i = 0; i < 4; i++)
#pragma unroll
                for (int j = 0; j < 4; j++)
                    acc[i][j] = MFMA16(av[i], bv[j], acc[i][j]);
        }
        __syncthreads();
    }
    if (mode < 2) {
        h_t* C = (mode == 0) ? Qh : Kh;
#pragma unroll
        for (int i = 0; i < 4; i++) {
            size_t r0 = m0 + wr + i * 16 + q16 * 4;
#pragma unroll
            for (int j = 0; j < 4; j++) {
                size_t c = n0 + wc + j * 16 + l16;
#pragma unroll
                for (int r = 0; r < 4; r++)
                    C[(r0 + r) * N + c] = (h_t)acc[i][j][r];
            }
        }
    } else {
#pragma unroll
        for (int i = 0; i < 4; i++) {
            size_t gm = m0 + wr + i * 16 + q16 * 4;
            size_t b = gm >> 11;
            size_t n = gm & 2047;
#pragma unroll
            for (int j = 0; j < 4; j++) {
                size_t d = n0 + wc + j * 16 + l16;
                float bias = bo[d];
                h4 hv = {(h_t)(acc[i][j][0] + bias), (h_t)(acc[i][j][1] + bias),
                         (h_t)(acc[i][j][2] + bias), (h_t)(acc[i][j][3] + bias)};
                *(h4*)&Vt[(b * 512 + d) * 2048 + n] = hv;
            }
        }
    }
}

// ---------------- flash attention, Q-tile 128, key-half split ----------------
// 256 blocks x 512 threads. QK^T: 8 waves = 4 row-groups(32) x 2 key-groups(64),
// frag reads 24/chunk/wave (was 36). Staging pipeline identical to R9 (double
// buffer, counted vmcnt(8)). Softmax: wave-local partials over 64 keys, then
// pairwise cross-wave combine via LDS pm/psv (+1 barrier). PV unchanged.
__global__ __launch_bounds__(512, 2) void k_attn(const h_t* __restrict__ Qh,
                                                 const h_t* __restrict__ Kh,
                                                 const h_t* __restrict__ Vt,
                                                 h_t* __restrict__ Obar,
                                                 float2* __restrict__ Ml) {
    __shared__ h_t smem[2][32768];  // 2 x 64KB: buf[i] = Qs(16384) + Ks(16384)
    __shared__ float arow[128];
    __shared__ float pm[8][32];     // per-wave partial row max
    __shared__ float psv[8][32];    // per-wave partial row expsum
    h_t* Ps = &smem[1][0];          // 17408 halves, aliases buf1 (PV phase only)

    int t = threadIdx.x, w = t >> 6, lane = t & 63;
    int q16 = lane >> 4, l16 = lane & 15;
    int rg = w >> 1, kg = w & 1;    // QK^T tile: rows rg*32.., keys kg*64..
    int b = blockIdx.x & 7;
    int half = (blockIdx.x >> 3) & 1;
    int qt = blockIdx.x >> 4;
    int q0 = qt * 128;
    int kh0 = half * 1024;
    int rof = lane >> 4, g = lane & 15;

    const h_t* Qbase = Qh + ((size_t)b * 2048 + q0) * 1024;
    const h_t* Kbase = Kh + (size_t)b * 2048 * 1024;
    const h_t* Vbase = Vt + (size_t)b * 512 * 2048;

    // stage chunk (kt_, c_) of Q and K into buffer bsel (8 gl2lds per wave)
    auto STAGE = [&](int kt_, int c_, int bsel) {
#pragma unroll
        for (int j = 0; j < 4; j++) {
            int row = w * 16 + j * 4 + rof;
            int gsrc = g ^ (row & 7);
            gl2lds16(Qbase + (size_t)row * 1024 + c_ * 128 + gsrc * 8,
                     &smem[bsel][(w * 16 + j * 4) * 128]);
        }
        int kb_ = kh0 + kt_ * 128;
#pragma unroll
        for (int j = 0; j < 4; j++) {
            int row = w * 16 + j * 4 + rof;
            int gsrc = g ^ (row & 7);
            gl2lds16(Kbase + (size_t)(kb_ + row) * 1024 + c_ * 128 + gsrc * 8,
                     &smem[bsel][16384 + (w * 16 + j * 4) * 128]);
        }
    };

    f4 oacc[8][4] = {};
    float mrun[2][4] = {{-1e30f, -1e30f, -1e30f, -1e30f},
                        {-1e30f, -1e30f, -1e30f, -1e30f}};
    float lrun[2][4] = {};

    STAGE(0, 0, 0);  // prologue
    int cur = 0;

#pragma unroll 1
    for (int kt = 0; kt < 8; kt++) {
        int kb = kh0 + kt * 128;
        f4 sacc[2][4] = {};
        // ---- S = Q K^T over inner 1024 in 8 chunks of 128, pipelined ----
#pragma unroll 1
        for (int c = 0; c < 8; c++) {
            if (!(kt == 7 && c == 7)) {
                int nkt = (c == 7) ? kt + 1 : kt;
                int nc = (c == 7) ? 0 : c + 1;
                STAGE(nkt, nc, cur ^ 1);
                asm volatile("s_waitcnt vmcnt(8)" ::: "memory");
            } else {
                asm volatile("s_waitcnt vmcnt(0)" ::: "memory");
            }
            __builtin_amdgcn_s_barrier();   // all waves' chunk-c data landed
            asm volatile("" ::: "memory");
            const h_t* Qs = &smem[cur][0];
            const h_t* Ks = &smem[cur][16384];
#pragma unroll
            for (int ks = 0; ks < 4; ks++) {
                int ch = ks * 4 + q16;
                h8 av[2], bv[4];
#pragma unroll
                for (int i = 0; i < 2; i++) {
                    int row = rg * 32 + i * 16 + l16;
                    av[i] = *(const h8*)&Qs[row * 128 + ((ch ^ (row & 7)) << 3)];
                }
#pragma unroll
                for (int j = 0; j < 4; j++) {
                    int kr = kg * 64 + j * 16 + l16;
                    bv[j] = *(const h8*)&Ks[kr * 128 + ((ch ^ (kr & 7)) << 3)];
                }
#pragma unroll
                for (int i = 0; i < 2; i++)
#pragma unroll
                    for (int j = 0; j < 4; j++)
                        sacc[i][j] = MFMA16(av[i], bv[j], sacc[i][j]);
            }
            asm volatile("" ::: "memory");
            __builtin_amdgcn_s_barrier();   // all waves done reading buf[cur]
            cur ^= 1;
        }
        // ---- softmax: wave-local over 64 keys, then pairwise combine ----
        float mt[2][4], st[2][4], beta[2][4];
#pragma unroll
        for (int i = 0; i < 2; i++)
#pragma unroll
            for (int r = 0; r < 4; r++) {
                float m = sacc[i][0][r];
#pragma unroll
                for (int j = 1; j < 4; j++) m = fmaxf(m, sacc[i][j][r]);
                mt[i][r] = m;
            }
#pragma unroll
        for (int m = 1; m <= 8; m <<= 1)
#pragma unroll
            for (int i = 0; i < 2; i++)
#pragma unroll
                for (int r = 0; r < 4; r++)
                    mt[i][r] = fmaxf(mt[i][r], __shfl_xor(mt[i][r], m, 64));
#pragma unroll
        for (int i = 0; i < 2; i++)
#pragma unroll
            for (int r = 0; r < 4; r++) {
                float s = 0.f;
#pragma unroll
                for (int j = 0; j < 4; j++) {
                    float e = __expf(sacc[i][j][r] - mt[i][r]);
                    sacc[i][j][r] = e;
                    s += e;
                }
                st[i][r] = s;
            }
#pragma unroll
        for (int m = 1; m <= 8; m <<= 1)
#pragma unroll
            for (int i = 0; i < 2; i++)
#pragma unroll
                for (int r = 0; r < 4; r++)
                    st[i][r] += __shfl_xor(st[i][r], m, 64);
        if (l16 == 0) {
#pragma unroll
            for (int i = 0; i < 2; i++)
#pragma unroll
                for (int r = 0; r < 4; r++) {
                    pm[w][i * 16 + q16 * 4 + r] = mt[i][r];
                    psv[w][i * 16 + q16 * 4 + r] = st[i][r];
                }
        }
        asm volatile("s_waitcnt lgkmcnt(0)" ::: "memory");
        __builtin_amdgcn_s_barrier();   // partials visible
        asm volatile("" ::: "memory");
#pragma unroll
        for (int i = 0; i < 2; i++)
#pragma unroll
            for (int r = 0; r < 4; r++) {
                int rloc = i * 16 + q16 * 4 + r;
                float pmp = pm[w ^ 1][rloc];
                float psp = psv[w ^ 1][rloc];
                float M = fmaxf(mt[i][r], pmp);
                float S = st[i][r] * __expf(mt[i][r] - M) + psp * __expf(pmp - M);
                float mo = mrun[i][r];
                float mn = fmaxf(mo, M);
                float a = __expf(mo - mn);
                lrun[i][r] = lrun[i][r] * a + S * __expf(M - mn);
                beta[i][r] = __expf(mt[i][r] - mn);
                mrun[i][r] = mn;
                if (kg == 0 && l16 == 0) arow[rg * 32 + rloc] = a;
            }
        // P (rescaled) -> LDS (aliases buf1; chunk 7 fully consumed), C->A layout
#pragma unroll
        for (int i = 0; i < 2; i++)
#pragma unroll
            for (int j = 0; j < 4; j++)
#pragma unroll
                for (int r = 0; r < 4; r++)
                    Ps[(rg * 32 + i * 16 + q16 * 4 + r) * 136 + kg * 64 + j * 16 + l16] =
                        (h_t)(sacc[i][j][r] * beta[i][r]);
        asm volatile("s_waitcnt lgkmcnt(0)" ::: "memory");
        __builtin_amdgcn_s_barrier();   // Ps + arow visible to all waves
        asm volatile("" ::: "memory");
        // ---- rescale O, then O += P @ V'' (wave owns 64 of 512 d-cols) ----
#pragma unroll
        for (int i = 0; i < 8; i++) {
#pragma unroll
            for (int r = 0; r < 4; r++) {
                float a = arow[i * 16 + q16 * 4 + r];
#pragma unroll
                for (int j = 0; j < 4; j++) oacc[i][j][r] *= a;
            }
        }
#pragma unroll
        for (int ks = 0; ks < 4; ks++) {
            h8 vf[4];
#pragma unroll
            for (int j = 0; j < 4; j++) {
                int d = w * 64 + j * 16 + l16;
                vf[j] = *(const h8*)(Vbase + (size_t)d * 2048 + kb + ks * 32 + q16 * 8);
            }
#pragma unroll
            for (int i = 0; i < 8; i++) {
                h8 pf = *(const h8*)&Ps[(i * 16 + l16) * 136 + ks * 32 + q16 * 8];
#pragma unroll
                for (int j = 0; j < 4; j++)
                    oacc[i][j] = MFMA16(pf, vf[j], oacc[i][j]);
            }
        }
        asm volatile("s_waitcnt lgkmcnt(0)" ::: "memory");
        __builtin_amdgcn_s_barrier();   // Ps/arow/pm consumed; buf1 free
        asm volatile("" ::: "memory");
    }
    // ---- epilogue: partial O (normalized by this half's l), m/l out ----
    if (kg == 0 && l16 == 0) {
#pragma unroll
        for (int i = 0; i < 2; i++)
#pragma unroll
            for (int r = 0; r < 4; r++)
                arow[rg * 32 + i * 16 + q16 * 4 + r] = lrun[i][r];
    }
    __syncthreads();
    size_t obase = (size_t)(half * 8 + b) * 2048 + q0;
#pragma unroll
    for (int i = 0; i < 8; i++) {
#pragma unroll
        for (int r = 0; r < 4; r++) {
            int row = i * 16 + q16 * 4 + r;
            float inv = 1.f / arow[row];
#pragma unroll
            for (int j = 0; j < 4; j++) {
                int d = w * 64 + j * 16 + l16;
                Obar[(obase + row) * 512 + d] = (h_t)(oacc[i][j][r] * inv);
            }
        }
    }
    if (kg == 0 && l16 == 0) {
#pragma unroll
        for (int i = 0; i < 2; i++)
#pragma unroll
            for (int r = 0; r < 4; r++) {
                int row = rg * 32 + i * 16 + q16 * 4 + r;
                Ml[obase + row] = make_float2(mrun[i][r], lrun[i][r]);
            }
    }
}

// ---------------- combine the two key-halves ----------------
__global__ __launch_bounds__(256) void k_comb(const h_t* __restrict__ Obar,
                                              const float2* __restrict__ Ml,
                                              float* __restrict__ Out) {
    int gid = blockIdx.x * 256 + threadIdx.x;  // 2,097,152 = 16384 rows x 128 d4
    int d4 = gid & 127;
    int rg = gid >> 7;  // b*2048 + row
    float2 ml0 = Ml[rg], ml1 = Ml[16384 + rg];
    float m = fmaxf(ml0.x, ml1.x);
    float w0 = ml0.y * __expf(ml0.x - m);
    float w1 = ml1.y * __expf(ml1.x - m);
    float inv = 1.f / (w0 + w1);
    w0 *= inv;
    w1 *= inv;
    h4 o0 = *(const h4*)&Obar[(size_t)rg * 512 + d4 * 4];
    h4 o1 = *(const h4*)&Obar[((size_t)16384 + rg) * 512 + d4 * 4];
    float4 o;
    o.x = w0 * (float)o0[0] + w1 * (float)o1[0];
    o.y = w0 * (float)o0[1] + w1 * (float)o1[1];
    o.z = w0 * (float)o0[2] + w1 * (float)o1[2];
    o.w = w0 * (float)o0[3] + w1 * (float)o1[3];
    *(float4*)&Out[(size_t)rg * 512 + d4 * 4] = o;
}

// ---------------- host ----------------
extern "C" void kernel_launch(void* const* d_in, const int* in_sizes, int n_in,
                              void* d_out, int out_size, void* d_ws, size_t ws_size,
                              hipStream_t stream) {
    const float* S1 = (const float*)d_in[0];
    const float* S2 = (const float*)d_in[1];
    const float* Wq = (const float*)d_in[2];
    const float* Wk = (const float*)d_in[3];
    const float* Wv = (const float*)d_in[4];
    const float* Wo = (const float*)d_in[5];
    const float* bo = (const float*)d_in[6];
    float* Out = (float*)d_out;

    char* ws = (char*)d_ws;
    h_t* S2h  = (h_t*)(ws);                 // 16 MB  (dead after Q-proj)
    h_t* S1h  = (h_t*)(ws + 16777216);      // 16 MB  (dead after Vt-proj)
    h_t* Wqt  = (h_t*)(ws + 33554432);      // 1 MB
    h_t* Wkt  = (h_t*)(ws + 34603008);      // 1 MB
    h_t* Wvot = (h_t*)(ws + 35651584);      // 0.5 MB (dead after Vt-proj)
    h_t* Qh   = (h_t*)(ws + 36175872);      // 32 MB
    h_t* Kh   = (h_t*)(ws + 69730304);      // 32 MB
    h_t* Vt   = (h_t*)(ws + 103284736);     // 16 MB -> end 120,061,952
    // aliases (dead regions reused):
    h_t* Wot  = (h_t*)(ws + 36175872);      // 1 MB  [512][1024] (pre-Qh)
    h_t* Wvh  = (h_t*)(ws + 37224448);      // 1 MB  [512][1024] (pre-Qh)
    h_t* Obar = (h_t*)(ws);                 // 32 MB [2][8][2048][512] over S2h+S1h
    float2* Ml = (float2*)(ws + 35651584);  // 256 KB [2][16384] over Wvot

    k_cast3<<<16896, 256, 0, stream>>>(S1, S2, Wv, S1h, S2h, Wvh);
    k_transpose3<<<dim3(32, 32, 3), 256, 0, stream>>>(Wq, Wk, Wo, Wqt, Wkt, Wot);
    // Wvot[d][c] = sum_e Wot[d][e] * Wvh[c][e] = (Wv @ Wo)^T
    k_gemm<<<dim3(4, 4), 256, 0, stream>>>(Wot, Wvh, Wvot, 512, 512, 1024);
    // fused Q/K/V'' projections
    k_proj3<<<2560, 256, 0, stream>>>(S2h, S1h, Wqt, Wkt, Wvot, bo, Qh, Kh, Vt);
    k_attn<<<256, 512, 0, stream>>>(Qh, Kh, Vt, Obar, Ml);
    k_comb<<<8192, 256, 0, stream>>>(Obar, Ml, Out);
}

// Round 5
// 411.456 us; speedup vs baseline: 1.2370x; 1.2370x over previous
//
#include <hip/hip_runtime.h>

// CrossAttention: out = softmax((S2 Wq)(S1 Wk)^T) (S1 Wv) Wo + bo
// Refactored: Wvo = Wv@Wo;  V'' = S1@Wvo + bo;  out = softmax(QK^T) @ V''
// R11: two-pass attention (P materialized). The flash structure was cornered:
// oacc(128 f32/lane) + sacc left 0 register headroom (R7/R10 spills) and QK^T
// ran at 1.125 LDS-reads/MFMA (MfmaUtil 22%). Now:
//   k_qk: per (b,qt,kt) 128x128 S-tile = proven k_gemm loop (0.5 reads/MFMA)
//         + tile-LOCAL softmax stats epilogue; writes P=exp(S-M) fp16 + (M,L).
//   k_stats: per row, m_fin / 1/l_fin over the 16 kt tiles.
//   k_pv: O = sum_kt (P_kt * exp(M_kt-m_fin)) @ V'' as a GEMM; delta folded
//         into reg-staged P tiles; epilogue x 1/l_fin, fp32 direct to Out.
// No online softmax, no oacc, no k_comb/Obar. P=64MB exceeds the proven ws
// budget -> two sequential qt-halves; P_half (32MB) aliases dead S2h+S1h,
// Mkt/MF alias dead Wqt/Wkt. P_half is L3-resident for k_pv.

typedef _Float16 h_t;
typedef _Float16 h8 __attribute__((ext_vector_type(8)));
typedef _Float16 h4 __attribute__((ext_vector_type(4)));
typedef float f4 __attribute__((ext_vector_type(4)));

#define MFMA16(a, b, c) __builtin_amdgcn_mfma_f32_16x16x32_f16(a, b, c, 0, 0, 0)

typedef const __attribute__((address_space(1))) void* gas_t;
typedef __attribute__((address_space(3))) void* las_t;

__device__ __forceinline__ void gl2lds16(const void* g, void* l) {
    __builtin_amdgcn_global_load_lds((gas_t)g, (las_t)l, 16, 0, 0);
}

// ---------------- merged cast fp32 -> fp16: S1, S2, Wv ----------------
__global__ __launch_bounds__(256) void k_cast3(const float* __restrict__ S1,
                                               const float* __restrict__ S2,
                                               const float* __restrict__ Wv,
                                               h_t* __restrict__ S1h,
                                               h_t* __restrict__ S2h,
                                               h_t* __restrict__ Wvh) {
    long i = (long)blockIdx.x * 256 + threadIdx.x;  // f4 index
    const long n = 2097152;                          // S1/S2 f4 count
    const float* src;
    h_t* dst;
    long off;
    if (i < n) { src = S1; dst = S1h; off = i; }
    else if (i < 2 * n) { src = S2; dst = S2h; off = i - n; }
    else { src = Wv; dst = Wvh; off = i - 2 * n; }
    float4 v = *((const float4*)src + off);
    h4 h = {(h_t)v.x, (h_t)v.y, (h_t)v.z, (h_t)v.w};
    *((h4*)dst + off) = h;
}

// ---------------- merged transpose+cast: Wq, Wk, Wo -> [N][K] f16 ----------------
__global__ __launch_bounds__(256) void k_transpose3(const float* __restrict__ Wq,
                                                    const float* __restrict__ Wk,
                                                    const float* __restrict__ Wo,
                                                    h_t* __restrict__ Wqt,
                                                    h_t* __restrict__ Wkt,
                                                    h_t* __restrict__ Wot) {
    const float* in;
    h_t* out;
    int K, N;
    if (blockIdx.z == 0) { in = Wq; out = Wqt; K = 512; N = 1024; }
    else if (blockIdx.z == 1) { in = Wk; out = Wkt; K = 512; N = 1024; }
    else { in = Wo; out = Wot; K = 1024; N = 512; }
    int kb = blockIdx.y * 32, nb = blockIdx.x * 32;
    if (kb >= K || nb >= N) return;
    __shared__ float tile[32][33];
    int x = threadIdx.x & 31, y = threadIdx.x >> 5;
#pragma unroll
    for (int j = 0; j < 4; j++)
        tile[y + j * 8][x] = in[(size_t)(kb + y + j * 8) * N + nb + x];
    __syncthreads();
#pragma unroll
    for (int j = 0; j < 4; j++)
        out[(size_t)(nb + y + j * 8) * K + kb + x] = (h_t)tile[x][y + j * 8];
}

// ---------------- m97-style NT GEMM: C[M][N] f16 = A[M][K] x Bt[N][K]^T ------------
__global__ __launch_bounds__(256) void k_gemm(const h_t* __restrict__ A,
                                              const h_t* __restrict__ Bt,
                                              h_t* __restrict__ C,
                                              int M, int N, int K) {
    __shared__ h_t As[128 * 64];
    __shared__ h_t Bs[128 * 64];
    int t = threadIdx.x, w = t >> 6, lane = t & 63;
    int q16 = lane >> 4, l16 = lane & 15;
    size_t m0 = (size_t)blockIdx.x * 128, n0 = (size_t)blockIdx.y * 128;
    int wr = (w >> 1) * 64, wc = (w & 1) * 64;
    f4 acc[4][4] = {};

    for (int k0 = 0; k0 < K; k0 += 64) {
#pragma unroll
        for (int j = 0; j < 4; j++) {
            int q = w * 4 + j;
            int row = q * 8 + (lane >> 3);
            int ks = (((lane & 7) ^ (row & 7)) << 3);
            gl2lds16(A + (m0 + row) * K + k0 + ks, &As[q * 512]);
            gl2lds16(Bt + (n0 + row) * K + k0 + ks, &Bs[q * 512]);
        }
        __syncthreads();
#pragma unroll
        for (int ks = 0; ks < 2; ks++) {
            h8 av[4], bv[4];
#pragma unroll
            for (int i = 0; i < 4; i++) {
                int row = wr + i * 16 + l16;
                int ch = ks * 4 + q16;
                av[i] = *(const h8*)&As[row * 64 + ((ch ^ (row & 7)) << 3)];
            }
#pragma unroll
            for (int j = 0; j < 4; j++) {
                int row = wc + j * 16 + l16;
                int ch = ks * 4 + q16;
                bv[j] = *(const h8*)&Bs[row * 64 + ((ch ^ (row & 7)) << 3)];
            }
#pragma unroll
            for (int i = 0; i < 4; i++)
#pragma unroll
                for (int j = 0; j < 4; j++)
                    acc[i][j] = MFMA16(av[i], bv[j], acc[i][j]);
        }
        __syncthreads();
    }
#pragma unroll
    for (int i = 0; i < 4; i++) {
        size_t r0 = m0 + wr + i * 16 + q16 * 4;
#pragma unroll
        for (int j = 0; j < 4; j++) {
            size_t c = n0 + wc + j * 16 + l16;
#pragma unroll
            for (int r = 0; r < 4; r++)
                C[(r0 + r) * N + c] = (h_t)acc[i][j][r];
        }
    }
}

// ---------------- fused Q/K/V'' projections (one launch, 2560 blocks) -------------
__global__ __launch_bounds__(256) void k_proj3(const h_t* __restrict__ S2h,
                                               const h_t* __restrict__ S1h,
                                               const h_t* __restrict__ Wqt,
                                               const h_t* __restrict__ Wkt,
                                               const h_t* __restrict__ Wvot,
                                               const float* __restrict__ bo,
                                               h_t* __restrict__ Qh,
                                               h_t* __restrict__ Kh,
                                               h_t* __restrict__ Vt) {
    __shared__ h_t As[128 * 64];
    __shared__ h_t Bs[128 * 64];
    int t = threadIdx.x, w = t >> 6, lane = t & 63;
    int q16 = lane >> 4, l16 = lane & 15;
    int id = blockIdx.x;
    const h_t* A;
    const h_t* Bt;
    int N, mode;
    size_t m0, n0;
    if (id < 1024) {
        mode = 0; A = S2h; Bt = Wqt; N = 1024;
        m0 = (size_t)(id >> 3) * 128; n0 = (size_t)(id & 7) * 128;
    } else if (id < 2048) {
        mode = 1; A = S1h; Bt = Wkt; N = 1024;
        id -= 1024; m0 = (size_t)(id >> 3) * 128; n0 = (size_t)(id & 7) * 128;
    } else {
        mode = 2; A = S1h; Bt = Wvot; N = 512;
        id -= 2048; m0 = (size_t)(id >> 2) * 128; n0 = (size_t)(id & 3) * 128;
    }
    const int K = 512;
    int wr = (w >> 1) * 64, wc = (w & 1) * 64;
    f4 acc[4][4] = {};

    for (int k0 = 0; k0 < K; k0 += 64) {
#pragma unroll
        for (int j = 0; j < 4; j++) {
            int q = w * 4 + j;
            int row = q * 8 + (lane >> 3);
            int ks = (((lane & 7) ^ (row & 7)) << 3);
            gl2lds16(A + (m0 + row) * K + k0 + ks, &As[q * 512]);
            gl2lds16(Bt + (n0 + row) * K + k0 + ks, &Bs[q * 512]);
        }
        __syncthreads();
#pragma unroll
        for (int ks = 0; ks < 2; ks++) {
            h8 av[4], bv[4];
#pragma unroll
            for (int i = 0; i < 4; i++) {
                int row = wr + i * 16 + l16;
                int ch = ks * 4 + q16;
                av[i] = *(const h8*)&As[row * 64 + ((ch ^ (row & 7)) << 3)];
            }
#pragma unroll
            for (int j = 0; j < 4; j++) {
                int row = wc + j * 16 + l16;
                int ch = ks * 4 + q16;
                bv[j] = *(const h8*)&Bs[row * 64 + ((ch ^ (row & 7)) << 3)];
            }
#pragma unroll
            for (int i = 0; i < 4; i++)
#pragma unroll
                for (int j = 0; j < 4; j++)
                    acc[i][j] = MFMA16(av[i], bv[j], acc[i][j]);
        }
        __syncthreads();
    }
    if (mode < 2) {
        h_t* C = (mode == 0) ? Qh : Kh;
#pragma unroll
        for (int i = 0; i < 4; i++) {
            size_t r0 = m0 + wr + i * 16 + q16 * 4;
#pragma unroll
            for (int j = 0; j < 4; j++) {
                size_t c = n0 + wc + j * 16 + l16;
#pragma unroll
                for (int r = 0; r < 4; r++)
                    C[(r0 + r) * N + c] = (h_t)acc[i][j][r];
            }
        }
    } else {
#pragma unroll
        for (int i = 0; i < 4; i++) {
            size_t gm = m0 + wr + i * 16 + q16 * 4;
            size_t b = gm >> 11;
            size_t n = gm & 2047;
#pragma unroll
            for (int j = 0; j < 4; j++) {
                size_t d = n0 + wc + j * 16 + l16;
                float bias = bo[d];
                h4 hv = {(h_t)(acc[i][j][0] + bias), (h_t)(acc[i][j][1] + bias),
                         (h_t)(acc[i][j][2] + bias), (h_t)(acc[i][j][3] + bias)};
                *(h4*)&Vt[(b * 512 + d) * 2048 + n] = hv;
            }
        }
    }
}

// ---------------- pass 1: S-tile GEMM + local softmax stats + P ----------------
// grid (qt 8, kt 16, b 8), 256 thr. Per block: S = Q[128 rows] K[128 keys]^T
// over inner 1024 (k_gemm loop). Epilogue: tile-local row max M / sum L
// (cross-wave pair exchange via LDS), P = exp(S - M) fp16 staged through LDS
// for coalesced store, stats (M, L) per row to Mkt.
__global__ __launch_bounds__(256) void k_qk(const h_t* __restrict__ Qh,
                                            const h_t* __restrict__ Kh,
                                            h_t* __restrict__ P,
                                            float2* __restrict__ Mkt,
                                            int qh) {
    __shared__ h_t sm[16384];       // As(8192) + Bs(8192); reused as P-stage
    __shared__ float pmx[2][128], psm[2][128];
    h_t* As = sm;
    h_t* Bs = sm + 8192;
    int t = threadIdx.x, w = t >> 6, lane = t & 63;
    int q16 = lane >> 4, l16 = lane & 15;
    int qt = blockIdx.x, kt = blockIdx.y, b = blockIdx.z;
    const h_t* A = Qh + ((size_t)b * 2048 + qh * 1024 + qt * 128) * 1024;
    const h_t* Bt = Kh + ((size_t)b * 2048 + kt * 128) * 1024;
    int wr = (w >> 1) * 64, wc = (w & 1) * 64;
    f4 acc[4][4] = {};

    for (int k0 = 0; k0 < 1024; k0 += 64) {
#pragma unroll
        for (int j = 0; j < 4; j++) {
            int q = w * 4 + j;
            int row = q * 8 + (lane >> 3);
            int ks = (((lane & 7) ^ (row & 7)) << 3);
            gl2lds16(A + (size_t)row * 1024 + k0 + ks, &As[q * 512]);
            gl2lds16(Bt + (size_t)row * 1024 + k0 + ks, &Bs[q * 512]);
        }
        __syncthreads();
#pragma unroll
        for (int ks = 0; ks < 2; ks++) {
            h8 av[4], bv[4];
#pragma unroll
            for (int i = 0; i < 4; i++) {
                int row = wr + i * 16 + l16;
                int ch = ks * 4 + q16;
                av[i] = *(const h8*)&As[row * 64 + ((ch ^ (row & 7)) << 3)];
            }
#pragma unroll
            for (int j = 0; j < 4; j++) {
                int row = wc + j * 16 + l16;
                int ch = ks * 4 + q16;
                bv[j] = *(const h8*)&Bs[row * 64 + ((ch ^ (row & 7)) << 3)];
            }
#pragma unroll
            for (int i = 0; i < 4; i++)
#pragma unroll
                for (int j = 0; j < 4; j++)
                    acc[i][j] = MFMA16(av[i], bv[j], acc[i][j]);
        }
        __syncthreads();
    }
    // ---- tile-local softmax stats (rows x this kt's 128 keys) ----
    float lm[4][4], ls[4][4];
#pragma unroll
    for (int i = 0; i < 4; i++)
#pragma unroll
        for (int r = 0; r < 4; r++) {
            float m = acc[i][0][r];
#pragma unroll
            for (int j = 1; j < 4; j++) m = fmaxf(m, acc[i][j][r]);
            lm[i][r] = m;
        }
#pragma unroll
    for (int msk = 1; msk <= 8; msk <<= 1)
#pragma unroll
        for (int i = 0; i < 4; i++)
#pragma unroll
            for (int r = 0; r < 4; r++)
                lm[i][r] = fmaxf(lm[i][r], __shfl_xor(lm[i][r], msk, 64));
#pragma unroll
    for (int i = 0; i < 4; i++)
#pragma unroll
        for (int r = 0; r < 4; r++) {
            float s = 0.f;
#pragma unroll
            for (int j = 0; j < 4; j++) s += __expf(acc[i][j][r] - lm[i][r]);
            ls[i][r] = s;
        }
#pragma unroll
    for (int msk = 1; msk <= 8; msk <<= 1)
#pragma unroll
        for (int i = 0; i < 4; i++)
#pragma unroll
            for (int r = 0; r < 4; r++)
                ls[i][r] += __shfl_xor(ls[i][r], msk, 64);
    if (l16 == 0) {
#pragma unroll
        for (int i = 0; i < 4; i++)
#pragma unroll
            for (int r = 0; r < 4; r++) {
                pmx[w & 1][wr + i * 16 + q16 * 4 + r] = lm[i][r];
                psm[w & 1][wr + i * 16 + q16 * 4 + r] = ls[i][r];
            }
    }
    __syncthreads();
#pragma unroll
    for (int i = 0; i < 4; i++)
#pragma unroll
        for (int r = 0; r < 4; r++) {
            int row = wr + i * 16 + q16 * 4 + r;
            float om = pmx[(w & 1) ^ 1][row];
            float os = psm[(w & 1) ^ 1][row];
            float M = fmaxf(lm[i][r], om);
            float L = ls[i][r] * __expf(lm[i][r] - M) + os * __expf(om - M);
            lm[i][r] = M;
            ls[i][r] = L;
        }
    if ((w & 1) == 0 && l16 == 0) {
#pragma unroll
        for (int i = 0; i < 4; i++)
#pragma unroll
            for (int r = 0; r < 4; r++)
                Mkt[((size_t)b * 16 + kt) * 1024 + qt * 128 + wr + i * 16 + q16 * 4 + r] =
                    make_float2(lm[i][r], ls[i][r]);
    }
    // ---- P tile -> LDS fp16 (As/Bs dead), then coalesced global store ----
#pragma unroll
    for (int i = 0; i < 4; i++)
#pragma unroll
        for (int j = 0; j < 4; j++)
#pragma unroll
            for (int r = 0; r < 4; r++)
                sm[(wr + i * 16 + q16 * 4 + r) * 128 + wc + j * 16 + l16] =
                    (h_t)__expf(acc[i][j][r] - lm[i][r]);
    __syncthreads();
    size_t Pbase = ((size_t)b * 1024 + qt * 128) * 2048 + (size_t)kt * 128;
#pragma unroll
    for (int p = 0; p < 8; p++) {
        int row = p * 16 + (t >> 4);
        int c8 = (t & 15) * 8;
        *(h8*)(P + Pbase + (size_t)row * 2048 + c8) = *(const h8*)&sm[row * 128 + c8];
    }
}

// ---------------- pass 1.5: per-row final stats over 16 kt tiles ----------------
__global__ __launch_bounds__(256) void k_stats(const float2* __restrict__ Mkt,
                                               float2* __restrict__ MF) {
    int r = blockIdx.x * 256 + threadIdx.x;  // 0..8191
    int b = r >> 10, rowl = r & 1023;
    float2 v[16];
    float m = -1e30f;
#pragma unroll
    for (int kt = 0; kt < 16; kt++) {
        v[kt] = Mkt[((size_t)b * 16 + kt) * 1024 + rowl];
        m = fmaxf(m, v[kt].x);
    }
    float l = 0.f;
#pragma unroll
    for (int kt = 0; kt < 16; kt++) l += v[kt].y * __expf(v[kt].x - m);
    MF[(size_t)b * 1024 + rowl] = make_float2(m, 1.f / l);
}

// ---------------- pass 2: O = sum_kt (P_kt * delta) @ V'', x 1/l_fin ----------------
// grid (rt 16, dt 4, b 8) = 512 blocks, 256 thr. Tile 64 rows x 128 d, keys
// 0..2047 in BK=64 steps. P reg-staged with delta=exp(M_kt-m_fin) folded in;
// V'' via gl2lds. Epilogue: fp32 Out = acc * (1/l_fin).
__global__ __launch_bounds__(256) void k_pv(const h_t* __restrict__ P,
                                            const h_t* __restrict__ Vt,
                                            const float2* __restrict__ Mkt,
                                            const float2* __restrict__ MF,
                                            float* __restrict__ Out,
                                            int qh) {
    __shared__ h_t As[64 * 64];     // P-tile 8 KB (delta-scaled)
    __shared__ h_t Bs[128 * 64];    // V-tile 16 KB
    int t = threadIdx.x, w = t >> 6, lane = t & 63;
    int q16 = lane >> 4, l16 = lane & 15;
    int rt = blockIdx.x, dt = blockIdx.y, b = blockIdx.z;
    int rg = w >> 1, dg = w & 1;
    int sr = t >> 3, sc = t & 7;    // staging coords: row base / col octet
    float mf0 = MF[(size_t)b * 1024 + rt * 64 + sr].x;
    float mf1 = MF[(size_t)b * 1024 + rt * 64 + 32 + sr].x;
    const h_t* Pb = P + ((size_t)b * 1024 + rt * 64) * 2048;
    const h_t* Vb = Vt + ((size_t)b * 512 + dt * 128) * 2048;
    f4 acc[2][4] = {};

    for (int k0 = 0; k0 < 2048; k0 += 64) {
        int kt = k0 >> 7;
#pragma unroll
        for (int p = 0; p < 2; p++) {
            int r_ = p * 32 + sr;
            float mfin = p ? mf1 : mf0;
            float2 mk = Mkt[((size_t)b * 16 + kt) * 1024 + rt * 64 + r_];
            float dl = __expf(mk.x - mfin);
            h_t dh = (h_t)dl;
            h8 dv = {dh, dh, dh, dh, dh, dh, dh, dh};
            h8 v = *(const h8*)(Pb + (size_t)r_ * 2048 + k0 + sc * 8);
            v = v * dv;
            *(h8*)&As[r_ * 64 + ((sc ^ (r_ & 7)) << 3)] = v;
        }
#pragma unroll
        for (int j = 0; j < 4; j++) {
            int q = w * 4 + j;
            int row = q * 8 + (lane >> 3);
            int ks = (((lane & 7) ^ (row & 7)) << 3);
            gl2lds16(Vb + (size_t)row * 2048 + k0 + ks, &Bs[q * 512]);
        }
        __syncthreads();
#pragma unroll
        for (int ks = 0; ks < 2; ks++) {
            int ch = ks * 4 + q16;
            h8 av[2], bv[4];
#pragma unroll
            for (int i = 0; i < 2; i++) {
                int row = rg * 32 + i * 16 + l16;
                av[i] = *(const h8*)&As[row * 64 + ((ch ^ (row & 7)) << 3)];
            }
#pragma unroll
            for (int j = 0; j < 4; j++) {
                int dr = dg * 64 + j * 16 + l16;
                bv[j] = *(const h8*)&Bs[dr * 64 + ((ch ^ (dr & 7)) << 3)];
            }
#pragma unroll
            for (int i = 0; i < 2; i++)
#pragma unroll
                for (int j = 0; j < 4; j++)
                    acc[i][j] = MFMA16(av[i], bv[j], acc[i][j]);
        }
        __syncthreads();
    }
#pragma unroll
    for (int i = 0; i < 2; i++)
#pragma unroll
        for (int rr = 0; rr < 4; rr++) {
            int row = rg * 32 + i * 16 + q16 * 4 + rr;
            float linv = MF[(size_t)b * 1024 + rt * 64 + row].y;
#pragma unroll
            for (int j = 0; j < 4; j++) {
                int d = dt * 128 + dg * 64 + j * 16 + l16;
                Out[((size_t)b * 2048 + qh * 1024 + rt * 64 + row) * 512 + d] =
                    acc[i][j][rr] * linv;
            }
        }
}

// ---------------- host ----------------
extern "C" void kernel_launch(void* const* d_in, const int* in_sizes, int n_in,
                              void* d_out, int out_size, void* d_ws, size_t ws_size,
                              hipStream_t stream) {
    const float* S1 = (const float*)d_in[0];
    const float* S2 = (const float*)d_in[1];
    const float* Wq = (const float*)d_in[2];
    const float* Wk = (const float*)d_in[3];
    const float* Wv = (const float*)d_in[4];
    const float* Wo = (const float*)d_in[5];
    const float* bo = (const float*)d_in[6];
    float* Out = (float*)d_out;

    char* ws = (char*)d_ws;
    h_t* S2h  = (h_t*)(ws);                 // 16 MB  (dead after proj3)
    h_t* S1h  = (h_t*)(ws + 16777216);      // 16 MB  (dead after proj3)
    h_t* Wqt  = (h_t*)(ws + 33554432);      // 1 MB   (dead after proj3)
    h_t* Wkt  = (h_t*)(ws + 34603008);      // 1 MB   (dead after proj3)
    h_t* Wvot = (h_t*)(ws + 35651584);      // 0.5 MB (dead after proj3)
    h_t* Qh   = (h_t*)(ws + 36175872);      // 32 MB
    h_t* Kh   = (h_t*)(ws + 69730304);      // 32 MB
    h_t* Vt   = (h_t*)(ws + 103284736);     // 16 MB -> end 120,061,952
    // aliases (dead regions reused):
    h_t* Wot  = (h_t*)(ws + 36175872);      // 1 MB [512][1024] (pre-Qh)
    h_t* Wvh  = (h_t*)(ws + 37224448);      // 1 MB [512][1024] (pre-Qh)
    h_t* Phb  = (h_t*)(ws);                 // 32 MB P_half [8][1024][2048] over S2h+S1h
    float2* Mkt = (float2*)(ws + 33554432); // 1 MB [8][16][1024] over Wqt
    float2* MF  = (float2*)(ws + 34603008); // 64 KB [8][1024] over Wkt

    k_cast3<<<16896, 256, 0, stream>>>(S1, S2, Wv, S1h, S2h, Wvh);
    k_transpose3<<<dim3(32, 32, 3), 256, 0, stream>>>(Wq, Wk, Wo, Wqt, Wkt, Wot);
    // Wvot[d][c] = sum_e Wot[d][e] * Wvh[c][e] = (Wv @ Wo)^T
    k_gemm<<<dim3(4, 4), 256, 0, stream>>>(Wot, Wvh, Wvot, 512, 512, 1024);
    // fused Q/K/V'' projections
    k_proj3<<<2560, 256, 0, stream>>>(S2h, S1h, Wqt, Wkt, Wvot, bo, Qh, Kh, Vt);
    // two-pass attention, two sequential qt-halves (P_half = 32 MB)
    for (int qh = 0; qh < 2; qh++) {
        k_qk<<<dim3(8, 16, 8), 256, 0, stream>>>(Qh, Kh, Phb, Mkt, qh);
        k_stats<<<32, 256, 0, stream>>>(Mkt, MF);
        k_pv<<<dim3(16, 4, 8), 256, 0, stream>>>(Phb, Vt, Mkt, MF, Out, qh);
    }
}

// Round 6
// 326.386 us; speedup vs baseline: 1.5594x; 1.2606x over previous
//
#include <hip/hip_runtime.h>

// CrossAttention: out = softmax((S2 Wq)(S1 Wk)^T) (S1 Wv) Wo + bo
// R12: algebraic fold. S = S2 (Wq Wk^T) S1^T, so precompute
//   Wkq[c][d2] = sum_e Wk[c,e] Wq[d2,e]   (512x512, tiny GEMM)
//   T = S2 @ Wkq^T                         (16384x512, inner 512)
//   S-tiles = T @ S1^T                     (inner 512, was 1024)
// eliminating the Q/K projections (-34 GFLOP, -64MB Qh/Kh traffic) and
// halving k_qk's K-loop (-34 GFLOP). V path unchanged: Wvo = Wv@Wo,
// V'' = S1@Wvo + bo (transposed store). Two-pass attention from R11 kept:
// k_qk (S-tile GEMM + local stats + P), k_stats, k_pv (delta-folded PV GEMM).
// S1h stays live through k_qk -> workspace re-laid-out (peak ~102 MB).

typedef _Float16 h_t;
typedef _Float16 h8 __attribute__((ext_vector_type(8)));
typedef _Float16 h4 __attribute__((ext_vector_type(4)));
typedef float f4 __attribute__((ext_vector_type(4)));

#define MFMA16(a, b, c) __builtin_amdgcn_mfma_f32_16x16x32_f16(a, b, c, 0, 0, 0)

typedef const __attribute__((address_space(1))) void* gas_t;
typedef __attribute__((address_space(3))) void* las_t;

__device__ __forceinline__ void gl2lds16(const void* g, void* l) {
    __builtin_amdgcn_global_load_lds((gas_t)g, (las_t)l, 16, 0, 0);
}

// ---------------- merged cast fp32 -> fp16: S1, S2, Wq, Wk, Wv ----------------
__global__ __launch_bounds__(256) void k_cast5(const float* __restrict__ S1,
                                               const float* __restrict__ S2,
                                               const float* __restrict__ Wq,
                                               const float* __restrict__ Wk,
                                               const float* __restrict__ Wv,
                                               h_t* __restrict__ S1h,
                                               h_t* __restrict__ S2h,
                                               h_t* __restrict__ Wqh,
                                               h_t* __restrict__ Wkh,
                                               h_t* __restrict__ Wvh) {
    long i = (long)blockIdx.x * 256 + threadIdx.x;  // f4 index
    const long n = 2097152;                          // S1/S2 f4 count
    const long wn = 131072;                          // weight f4 count
    const float* src;
    h_t* dst;
    long off;
    if (i < n) { src = S1; dst = S1h; off = i; }
    else if (i < 2 * n) { src = S2; dst = S2h; off = i - n; }
    else if (i < 2 * n + wn) { src = Wq; dst = Wqh; off = i - 2 * n; }
    else if (i < 2 * n + 2 * wn) { src = Wk; dst = Wkh; off = i - 2 * n - wn; }
    else { src = Wv; dst = Wvh; off = i - 2 * n - 2 * wn; }
    float4 v = *((const float4*)src + off);
    h4 h = {(h_t)v.x, (h_t)v.y, (h_t)v.z, (h_t)v.w};
    *((h4*)dst + off) = h;
}

// ---------------- transpose+cast: Wo [1024][512] -> Wot [512][1024] f16 -----------
__global__ __launch_bounds__(256) void k_transpose_o(const float* __restrict__ Wo,
                                                     h_t* __restrict__ Wot) {
    const int K = 1024, N = 512;
    int kb = blockIdx.y * 32, nb = blockIdx.x * 32;
    __shared__ float tile[32][33];
    int x = threadIdx.x & 31, y = threadIdx.x >> 5;
#pragma unroll
    for (int j = 0; j < 4; j++)
        tile[y + j * 8][x] = Wo[(size_t)(kb + y + j * 8) * N + nb + x];
    __syncthreads();
#pragma unroll
    for (int j = 0; j < 4; j++)
        Wot[(size_t)(nb + y + j * 8) * K + kb + x] = (h_t)tile[x][y + j * 8];
}

// ---------------- fused weight-fold GEMMs: Wkq and Wvot (32 blocks) ---------------
// id<16:  Wkq[c][d2]  = sum_e Wkh[c,e]  Wqh[d2,e]   (512x512, K=1024)
// id>=16: Wvot[d][c]  = sum_e Wot[d,e]  Wvh[c,e]    (512x512, K=1024)
__global__ __launch_bounds__(256) void k_wpre(const h_t* __restrict__ Wqh,
                                              const h_t* __restrict__ Wkh,
                                              const h_t* __restrict__ Wot,
                                              const h_t* __restrict__ Wvh,
                                              h_t* __restrict__ Wkq,
                                              h_t* __restrict__ Wvot) {
    __shared__ h_t As[128 * 64];
    __shared__ h_t Bs[128 * 64];
    int t = threadIdx.x, w = t >> 6, lane = t & 63;
    int q16 = lane >> 4, l16 = lane & 15;
    int id = blockIdx.x;
    const h_t* A;
    const h_t* Bt;
    h_t* C;
    if (id < 16) { A = Wkh; Bt = Wqh; C = Wkq; }
    else { id -= 16; A = Wot; Bt = Wvh; C = Wvot; }
    size_t m0 = (size_t)(id >> 2) * 128, n0 = (size_t)(id & 3) * 128;
    const int K = 1024, N = 512;
    int wr = (w >> 1) * 64, wc = (w & 1) * 64;
    f4 acc[4][4] = {};

    for (int k0 = 0; k0 < K; k0 += 64) {
#pragma unroll
        for (int j = 0; j < 4; j++) {
            int q = w * 4 + j;
            int row = q * 8 + (lane >> 3);
            int ks = (((lane & 7) ^ (row & 7)) << 3);
            gl2lds16(A + (m0 + row) * K + k0 + ks, &As[q * 512]);
            gl2lds16(Bt + (n0 + row) * K + k0 + ks, &Bs[q * 512]);
        }
        __syncthreads();
#pragma unroll
        for (int ks = 0; ks < 2; ks++) {
            h8 av[4], bv[4];
#pragma unroll
            for (int i = 0; i < 4; i++) {
                int row = wr + i * 16 + l16;
                int ch = ks * 4 + q16;
                av[i] = *(const h8*)&As[row * 64 + ((ch ^ (row & 7)) << 3)];
            }
#pragma unroll
            for (int j = 0; j < 4; j++) {
                int row = wc + j * 16 + l16;
                int ch = ks * 4 + q16;
                bv[j] = *(const h8*)&Bs[row * 64 + ((ch ^ (row & 7)) << 3)];
            }
#pragma unroll
            for (int i = 0; i < 4; i++)
#pragma unroll
                for (int j = 0; j < 4; j++)
                    acc[i][j] = MFMA16(av[i], bv[j], acc[i][j]);
        }
        __syncthreads();
    }
#pragma unroll
    for (int i = 0; i < 4; i++) {
        size_t r0 = m0 + wr + i * 16 + q16 * 4;
#pragma unroll
        for (int j = 0; j < 4; j++) {
            size_t c = n0 + wc + j * 16 + l16;
#pragma unroll
            for (int r = 0; r < 4; r++)
                C[(r0 + r) * N + c] = (h_t)acc[i][j][r];
        }
    }
}

// ---------------- fused T / V'' projections (1024 blocks) -------------------------
// blocks 0..511:  T  = S2h @ Wkq^T        [16384][512], K=512
// blocks 512..1023: Vt = (S1h @ Wvot^T + bo) stored transposed [b][d][n]
__global__ __launch_bounds__(256) void k_proj2(const h_t* __restrict__ S2h,
                                               const h_t* __restrict__ S1h,
                                               const h_t* __restrict__ Wkq,
                                               const h_t* __restrict__ Wvot,
                                               const float* __restrict__ bo,
                                               h_t* __restrict__ T,
                                               h_t* __restrict__ Vt) {
    __shared__ h_t As[128 * 64];
    __shared__ h_t Bs[128 * 64];
    int t = threadIdx.x, w = t >> 6, lane = t & 63;
    int q16 = lane >> 4, l16 = lane & 15;
    int id = blockIdx.x;
    int mode = id >> 9;
    id &= 511;
    const h_t* A = mode ? S1h : S2h;
    const h_t* Bt = mode ? Wvot : Wkq;
    size_t m0 = (size_t)(id >> 2) * 128, n0 = (size_t)(id & 3) * 128;
    const int K = 512, N = 512;
    int wr = (w >> 1) * 64, wc = (w & 1) * 64;
    f4 acc[4][4] = {};

    for (int k0 = 0; k0 < K; k0 += 64) {
#pragma unroll
        for (int j = 0; j < 4; j++) {
            int q = w * 4 + j;
            int row = q * 8 + (lane >> 3);
            int ks = (((lane & 7) ^ (row & 7)) << 3);
            gl2lds16(A + (m0 + row) * K + k0 + ks, &As[q * 512]);
            gl2lds16(Bt + (n0 + row) * K + k0 + ks, &Bs[q * 512]);
        }
        __syncthreads();
#pragma unroll
        for (int ks = 0; ks < 2; ks++) {
            h8 av[4], bv[4];
#pragma unroll
            for (int i = 0; i < 4; i++) {
                int row = wr + i * 16 + l16;
                int ch = ks * 4 + q16;
                av[i] = *(const h8*)&As[row * 64 + ((ch ^ (row & 7)) << 3)];
            }
#pragma unroll
            for (int j = 0; j < 4; j++) {
                int row = wc + j * 16 + l16;
                int ch = ks * 4 + q16;
                bv[j] = *(const h8*)&Bs[row * 64 + ((ch ^ (row & 7)) << 3)];
            }
#pragma unroll
            for (int i = 0; i < 4; i++)
#pragma unroll
                for (int j = 0; j < 4; j++)
                    acc[i][j] = MFMA16(av[i], bv[j], acc[i][j]);
        }
        __syncthreads();
    }
    if (mode == 0) {
#pragma unroll
        for (int i = 0; i < 4; i++) {
            size_t r0 = m0 + wr + i * 16 + q16 * 4;
#pragma unroll
            for (int j = 0; j < 4; j++) {
                size_t c = n0 + wc + j * 16 + l16;
#pragma unroll
                for (int r = 0; r < 4; r++)
                    T[(r0 + r) * 512 + c] = (h_t)acc[i][j][r];
            }
        }
    } else {
#pragma unroll
        for (int i = 0; i < 4; i++) {
            size_t gm = m0 + wr + i * 16 + q16 * 4;
            size_t b = gm >> 11;
            size_t n = gm & 2047;
#pragma unroll
            for (int j = 0; j < 4; j++) {
                size_t d = n0 + wc + j * 16 + l16;
                float bias = bo[d];
                h4 hv = {(h_t)(acc[i][j][0] + bias), (h_t)(acc[i][j][1] + bias),
                         (h_t)(acc[i][j][2] + bias), (h_t)(acc[i][j][3] + bias)};
                *(h4*)&Vt[(b * 512 + d) * 2048 + n] = hv;
            }
        }
    }
}

// ---------------- pass 1: S-tile GEMM (inner 512) + local stats + P ---------------
// grid (qt 8, kt 16, b 8), 256 thr. S = T[128 rows] @ S1h[128 keys]^T, K=512.
__global__ __launch_bounds__(256) void k_qk(const h_t* __restrict__ T,
                                            const h_t* __restrict__ S1h,
                                            h_t* __restrict__ P,
                                            float2* __restrict__ Mkt,
                                            int qh) {
    __shared__ h_t sm[16384];       // As(8192) + Bs(8192); reused as P-stage
    __shared__ float pmx[2][128], psm[2][128];
    h_t* As = sm;
    h_t* Bs = sm + 8192;
    int t = threadIdx.x, w = t >> 6, lane = t & 63;
    int q16 = lane >> 4, l16 = lane & 15;
    int qt = blockIdx.x, kt = blockIdx.y, b = blockIdx.z;
    const h_t* A = T + ((size_t)b * 2048 + qh * 1024 + qt * 128) * 512;
    const h_t* Bt = S1h + ((size_t)b * 2048 + kt * 128) * 512;
    int wr = (w >> 1) * 64, wc = (w & 1) * 64;
    f4 acc[4][4] = {};

    for (int k0 = 0; k0 < 512; k0 += 64) {
#pragma unroll
        for (int j = 0; j < 4; j++) {
            int q = w * 4 + j;
            int row = q * 8 + (lane >> 3);
            int ks = (((lane & 7) ^ (row & 7)) << 3);
            gl2lds16(A + (size_t)row * 512 + k0 + ks, &As[q * 512]);
            gl2lds16(Bt + (size_t)row * 512 + k0 + ks, &Bs[q * 512]);
        }
        __syncthreads();
#pragma unroll
        for (int ks = 0; ks < 2; ks++) {
            h8 av[4], bv[4];
#pragma unroll
            for (int i = 0; i < 4; i++) {
                int row = wr + i * 16 + l16;
                int ch = ks * 4 + q16;
                av[i] = *(const h8*)&As[row * 64 + ((ch ^ (row & 7)) << 3)];
            }
#pragma unroll
            for (int j = 0; j < 4; j++) {
                int row = wc + j * 16 + l16;
                int ch = ks * 4 + q16;
                bv[j] = *(const h8*)&Bs[row * 64 + ((ch ^ (row & 7)) << 3)];
            }
#pragma unroll
            for (int i = 0; i < 4; i++)
#pragma unroll
                for (int j = 0; j < 4; j++)
                    acc[i][j] = MFMA16(av[i], bv[j], acc[i][j]);
        }
        __syncthreads();
    }
    // ---- tile-local softmax stats (rows x this kt's 128 keys) ----
    float lm[4][4], ls[4][4];
#pragma unroll
    for (int i = 0; i < 4; i++)
#pragma unroll
        for (int r = 0; r < 4; r++) {
            float m = acc[i][0][r];
#pragma unroll
            for (int j = 1; j < 4; j++) m = fmaxf(m, acc[i][j][r]);
            lm[i][r] = m;
        }
#pragma unroll
    for (int msk = 1; msk <= 8; msk <<= 1)
#pragma unroll
        for (int i = 0; i < 4; i++)
#pragma unroll
            for (int r = 0; r < 4; r++)
                lm[i][r] = fmaxf(lm[i][r], __shfl_xor(lm[i][r], msk, 64));
#pragma unroll
    for (int i = 0; i < 4; i++)
#pragma unroll
        for (int r = 0; r < 4; r++) {
            float s = 0.f;
#pragma unroll
            for (int j = 0; j < 4; j++) s += __expf(acc[i][j][r] - lm[i][r]);
            ls[i][r] = s;
        }
#pragma unroll
    for (int msk = 1; msk <= 8; msk <<= 1)
#pragma unroll
        for (int i = 0; i < 4; i++)
#pragma unroll
            for (int r = 0; r < 4; r++)
                ls[i][r] += __shfl_xor(ls[i][r], msk, 64);
    if (l16 == 0) {
#pragma unroll
        for (int i = 0; i < 4; i++)
#pragma unroll
            for (int r = 0; r < 4; r++) {
                pmx[w & 1][wr + i * 16 + q16 * 4 + r] = lm[i][r];
                psm[w & 1][wr + i * 16 + q16 * 4 + r] = ls[i][r];
            }
    }
    __syncthreads();
#pragma unroll
    for (int i = 0; i < 4; i++)
#pragma unroll
        for (int r = 0; r < 4; r++) {
            int row = wr + i * 16 + q16 * 4 + r;
            float om = pmx[(w & 1) ^ 1][row];
            float os = psm[(w & 1) ^ 1][row];
            float M = fmaxf(lm[i][r], om);
            float L = ls[i][r] * __expf(lm[i][r] - M) + os * __expf(om - M);
            lm[i][r] = M;
            ls[i][r] = L;
        }
    if ((w & 1) == 0 && l16 == 0) {
#pragma unroll
        for (int i = 0; i < 4; i++)
#pragma unroll
            for (int r = 0; r < 4; r++)
                Mkt[((size_t)b * 16 + kt) * 1024 + qt * 128 + wr + i * 16 + q16 * 4 + r] =
                    make_float2(lm[i][r], ls[i][r]);
    }
    // ---- P tile -> LDS fp16 (As/Bs dead), then coalesced global store ----
#pragma unroll
    for (int i = 0; i < 4; i++)
#pragma unroll
        for (int j = 0; j < 4; j++)
#pragma unroll
            for (int r = 0; r < 4; r++)
                sm[(wr + i * 16 + q16 * 4 + r) * 128 + wc + j * 16 + l16] =
                    (h_t)__expf(acc[i][j][r] - lm[i][r]);
    __syncthreads();
    size_t Pbase = ((size_t)b * 1024 + qt * 128) * 2048 + (size_t)kt * 128;
#pragma unroll
    for (int p = 0; p < 8; p++) {
        int row = p * 16 + (t >> 4);
        int c8 = (t & 15) * 8;
        *(h8*)(P + Pbase + (size_t)row * 2048 + c8) = *(const h8*)&sm[row * 128 + c8];
    }
}

// ---------------- pass 1.5: per-row final stats over 16 kt tiles ----------------
__global__ __launch_bounds__(256) void k_stats(const float2* __restrict__ Mkt,
                                               float2* __restrict__ MF) {
    int r = blockIdx.x * 256 + threadIdx.x;  // 0..8191
    int b = r >> 10, rowl = r & 1023;
    float2 v[16];
    float m = -1e30f;
#pragma unroll
    for (int kt = 0; kt < 16; kt++) {
        v[kt] = Mkt[((size_t)b * 16 + kt) * 1024 + rowl];
        m = fmaxf(m, v[kt].x);
    }
    float l = 0.f;
#pragma unroll
    for (int kt = 0; kt < 16; kt++) l += v[kt].y * __expf(v[kt].x - m);
    MF[(size_t)b * 1024 + rowl] = make_float2(m, 1.f / l);
}

// ---------------- pass 2: O = sum_kt (P_kt * delta) @ V'', x 1/l_fin ----------------
// grid (rt 16, dt 4, b 8) = 512 blocks, 256 thr. Tile 64 rows x 128 d, keys
// 0..2047 in BK=64 steps. P reg-staged with delta=exp(M_kt-m_fin) folded in.
__global__ __launch_bounds__(256) void k_pv(const h_t* __restrict__ P,
                                            const h_t* __restrict__ Vt,
                                            const float2* __restrict__ Mkt,
                                            const float2* __restrict__ MF,
                                            float* __restrict__ Out,
                                            int qh) {
    __shared__ h_t As[64 * 64];     // P-tile 8 KB (delta-scaled)
    __shared__ h_t Bs[128 * 64];    // V-tile 16 KB
    int t = threadIdx.x, w = t >> 6, lane = t & 63;
    int q16 = lane >> 4, l16 = lane & 15;
    int rt = blockIdx.x, dt = blockIdx.y, b = blockIdx.z;
    int rg = w >> 1, dg = w & 1;
    int sr = t >> 3, sc = t & 7;    // staging coords: row base / col octet
    float mf0 = MF[(size_t)b * 1024 + rt * 64 + sr].x;
    float mf1 = MF[(size_t)b * 1024 + rt * 64 + 32 + sr].x;
    const h_t* Pb = P + ((size_t)b * 1024 + rt * 64) * 2048;
    const h_t* Vb = Vt + ((size_t)b * 512 + dt * 128) * 2048;
    f4 acc[2][4] = {};

    for (int k0 = 0; k0 < 2048; k0 += 64) {
        int kt = k0 >> 7;
#pragma unroll
        for (int p = 0; p < 2; p++) {
            int r_ = p * 32 + sr;
            float mfin = p ? mf1 : mf0;
            float2 mk = Mkt[((size_t)b * 16 + kt) * 1024 + rt * 64 + r_];
            float dl = __expf(mk.x - mfin);
            h_t dh = (h_t)dl;
            h8 dv = {dh, dh, dh, dh, dh, dh, dh, dh};
            h8 v = *(const h8*)(Pb + (size_t)r_ * 2048 + k0 + sc * 8);
            v = v * dv;
            *(h8*)&As[r_ * 64 + ((sc ^ (r_ & 7)) << 3)] = v;
        }
#pragma unroll
        for (int j = 0; j < 4; j++) {
            int q = w * 4 + j;
            int row = q * 8 + (lane >> 3);
            int ks = (((lane & 7) ^ (row & 7)) << 3);
            gl2lds16(Vb + (size_t)row * 2048 + k0 + ks, &Bs[q * 512]);
        }
        __syncthreads();
#pragma unroll
        for (int ks = 0; ks < 2; ks++) {
            int ch = ks * 4 + q16;
            h8 av[2], bv[4];
#pragma unroll
            for (int i = 0; i < 2; i++) {
                int row = rg * 32 + i * 16 + l16;
                av[i] = *(const h8*)&As[row * 64 + ((ch ^ (row & 7)) << 3)];
            }
#pragma unroll
            for (int j = 0; j < 4; j++) {
                int dr = dg * 64 + j * 16 + l16;
                bv[j] = *(const h8*)&Bs[dr * 64 + ((ch ^ (dr & 7)) << 3)];
            }
#pragma unroll
            for (int i = 0; i < 2; i++)
#pragma unroll
                for (int j = 0; j < 4; j++)
                    acc[i][j] = MFMA16(av[i], bv[j], acc[i][j]);
        }
        __syncthreads();
    }
#pragma unroll
    for (int i = 0; i < 2; i++)
#pragma unroll
        for (int rr = 0; rr < 4; rr++) {
            int row = rg * 32 + i * 16 + q16 * 4 + rr;
            float linv = MF[(size_t)b * 1024 + rt * 64 + row].y;
#pragma unroll
            for (int j = 0; j < 4; j++) {
                int d = dt * 128 + dg * 64 + j * 16 + l16;
                Out[((size_t)b * 2048 + qh * 1024 + rt * 64 + row) * 512 + d] =
                    acc[i][j][rr] * linv;
            }
        }
}

// ---------------- host ----------------
extern "C" void kernel_launch(void* const* d_in, const int* in_sizes, int n_in,
                              void* d_out, int out_size, void* d_ws, size_t ws_size,
                              hipStream_t stream) {
    const float* S1 = (const float*)d_in[0];
    const float* S2 = (const float*)d_in[1];
    const float* Wq = (const float*)d_in[2];
    const float* Wk = (const float*)d_in[3];
    const float* Wv = (const float*)d_in[4];
    const float* Wo = (const float*)d_in[5];
    const float* bo = (const float*)d_in[6];
    float* Out = (float*)d_out;

    char* ws = (char*)d_ws;
    h_t* S2h  = (h_t*)(ws);                  // 16 MB (dead after k_proj2)
    h_t* S1h  = (h_t*)(ws + 16777216);       // 16 MB (live through k_qk)
    h_t* Wqh  = (h_t*)(ws + 33554432);       // 1 MB  [512][1024]
    h_t* Wkh  = (h_t*)(ws + 34603008);       // 1 MB  [512][1024]
    h_t* Wvh  = (h_t*)(ws + 35651584);       // 1 MB  [512][1024]
    h_t* Wot  = (h_t*)(ws + 36700160);       // 1 MB  [512][1024]
    h_t* Wkq  = (h_t*)(ws + 37748736);       // 0.5 MB [512][512]
    h_t* Wvot = (h_t*)(ws + 38273024);       // 0.5 MB [512][512]
    h_t* T    = (h_t*)(ws + 38797312);       // 16 MB [16384][512]
    h_t* Vt   = (h_t*)(ws + 55574528);       // 16 MB [8][512][2048]
    h_t* Phb  = (h_t*)(ws + 72351744);       // 32 MB P_half [8][1024][2048]
    float2* Mkt = (float2*)(ws + 105906176); // 1 MB [8][16][1024]
    float2* MF  = (float2*)(ws + 106954752); // 64 KB [8][1024]
    // peak ~102 MB (< proven 120 MB budget)

    k_cast5<<<17920, 256, 0, stream>>>(S1, S2, Wq, Wk, Wv, S1h, S2h, Wqh, Wkh, Wvh);
    k_transpose_o<<<dim3(16, 32), 256, 0, stream>>>(Wo, Wot);
    k_wpre<<<32, 256, 0, stream>>>(Wqh, Wkh, Wot, Wvh, Wkq, Wvot);
    k_proj2<<<1024, 256, 0, stream>>>(S2h, S1h, Wkq, Wvot, bo, T, Vt);
    for (int qh = 0; qh < 2; qh++) {
        k_qk<<<dim3(8, 16, 8), 256, 0, stream>>>(T, S1h, Phb, Mkt, qh);
        k_stats<<<32, 256, 0, stream>>>(Mkt, MF);
        k_pv<<<dim3(16, 4, 8), 256, 0, stream>>>(Phb, Vt, Mkt, MF, Out, qh);
    }
}

// Round 7
// 293.204 us; speedup vs baseline: 1.7359x; 1.1132x over previous
//
#include <hip/hip_runtime.h>

// CrossAttention: out = softmax((S2 Wq)(S1 Wk)^T) (S1 Wv) Wo + bo
// R13 = R12 (algebraic fold: Wkq = Wq Wk^T pre-GEMM'd; T = S2 Wkq^T; V''= S1
// Wvo + bo; two-pass attention with P materialized) plus:
//  - exp2 domain: Wkq scaled by log2(e) at k_wpre -> every exp becomes bare
//    v_exp_f32 (exp2f), no mul. Algebraically exact.
//  - k_qk single-exp epilogue: e stored into acc during the sum pass; P-write
//    is e * exp2(lm_wave - M_tile) (16 exps not 64). ~40% fewer VALU ops.
//  - k_stats emits Dkt = exp2(M_kt - m_fin) fp16; k_pv inner loop has ZERO
//    transcendentals (loads Dkt h_t, kt-hoisted).
//  - single full P (64 MB), no qh halves: S2h+weights alias P (dead before
//    k_qk), Dkt/MF alias S1h (dead after k_qk). Peak ~119.5 MB.

typedef _Float16 h_t;
typedef _Float16 h8 __attribute__((ext_vector_type(8)));
typedef _Float16 h4 __attribute__((ext_vector_type(4)));
typedef float f4 __attribute__((ext_vector_type(4)));

#define MFMA16(a, b, c) __builtin_amdgcn_mfma_f32_16x16x32_f16(a, b, c, 0, 0, 0)

typedef const __attribute__((address_space(1))) void* gas_t;
typedef __attribute__((address_space(3))) void* las_t;

__device__ __forceinline__ void gl2lds16(const void* g, void* l) {
    __builtin_amdgcn_global_load_lds((gas_t)g, (las_t)l, 16, 0, 0);
}

// ---------------- merged cast fp32 -> fp16: S1, S2, Wq, Wk, Wv ----------------
__global__ __launch_bounds__(256) void k_cast5(const float* __restrict__ S1,
                                               const float* __restrict__ S2,
                                               const float* __restrict__ Wq,
                                               const float* __restrict__ Wk,
                                               const float* __restrict__ Wv,
                                               h_t* __restrict__ S1h,
                                               h_t* __restrict__ S2h,
                                               h_t* __restrict__ Wqh,
                                               h_t* __restrict__ Wkh,
                                               h_t* __restrict__ Wvh) {
    long i = (long)blockIdx.x * 256 + threadIdx.x;  // f4 index
    const long n = 2097152;                          // S1/S2 f4 count
    const long wn = 131072;                          // weight f4 count
    const float* src;
    h_t* dst;
    long off;
    if (i < n) { src = S1; dst = S1h; off = i; }
    else if (i < 2 * n) { src = S2; dst = S2h; off = i - n; }
    else if (i < 2 * n + wn) { src = Wq; dst = Wqh; off = i - 2 * n; }
    else if (i < 2 * n + 2 * wn) { src = Wk; dst = Wkh; off = i - 2 * n - wn; }
    else { src = Wv; dst = Wvh; off = i - 2 * n - 2 * wn; }
    float4 v = *((const float4*)src + off);
    h4 h = {(h_t)v.x, (h_t)v.y, (h_t)v.z, (h_t)v.w};
    *((h4*)dst + off) = h;
}

// ---------------- transpose+cast: Wo [1024][512] -> Wot [512][1024] f16 -----------
__global__ __launch_bounds__(256) void k_transpose_o(const float* __restrict__ Wo,
                                                     h_t* __restrict__ Wot) {
    const int K = 1024, N = 512;
    int kb = blockIdx.y * 32, nb = blockIdx.x * 32;
    __shared__ float tile[32][33];
    int x = threadIdx.x & 31, y = threadIdx.x >> 5;
#pragma unroll
    for (int j = 0; j < 4; j++)
        tile[y + j * 8][x] = Wo[(size_t)(kb + y + j * 8) * N + nb + x];
    __syncthreads();
#pragma unroll
    for (int j = 0; j < 4; j++)
        Wot[(size_t)(nb + y + j * 8) * K + kb + x] = (h_t)tile[x][y + j * 8];
}

// ---------------- fused weight-fold GEMMs: Wkq (x log2e) and Wvot ----------------
// id<16:  Wkq[c][d2]  = log2(e) * sum_e Wkh[c,e] Wqh[d2,e]   (512x512, K=1024)
// id>=16: Wvot[d][c]  =           sum_e Wot[d,e] Wvh[c,e]    (512x512, K=1024)
__global__ __launch_bounds__(256) void k_wpre(const h_t* __restrict__ Wqh,
                                              const h_t* __restrict__ Wkh,
                                              const h_t* __restrict__ Wot,
                                              const h_t* __restrict__ Wvh,
                                              h_t* __restrict__ Wkq,
                                              h_t* __restrict__ Wvot) {
    __shared__ h_t As[128 * 64];
    __shared__ h_t Bs[128 * 64];
    int t = threadIdx.x, w = t >> 6, lane = t & 63;
    int q16 = lane >> 4, l16 = lane & 15;
    int id = blockIdx.x;
    const h_t* A;
    const h_t* Bt;
    h_t* C;
    float oscale;
    if (id < 16) { A = Wkh; Bt = Wqh; C = Wkq; oscale = 1.44269504f; }
    else { id -= 16; A = Wot; Bt = Wvh; C = Wvot; oscale = 1.0f; }
    size_t m0 = (size_t)(id >> 2) * 128, n0 = (size_t)(id & 3) * 128;
    const int K = 1024, N = 512;
    int wr = (w >> 1) * 64, wc = (w & 1) * 64;
    f4 acc[4][4] = {};

    for (int k0 = 0; k0 < K; k0 += 64) {
#pragma unroll
        for (int j = 0; j < 4; j++) {
            int q = w * 4 + j;
            int row = q * 8 + (lane >> 3);
            int ks = (((lane & 7) ^ (row & 7)) << 3);
            gl2lds16(A + (m0 + row) * K + k0 + ks, &As[q * 512]);
            gl2lds16(Bt + (n0 + row) * K + k0 + ks, &Bs[q * 512]);
        }
        __syncthreads();
#pragma unroll
        for (int ks = 0; ks < 2; ks++) {
            h8 av[4], bv[4];
#pragma unroll
            for (int i = 0; i < 4; i++) {
                int row = wr + i * 16 + l16;
                int ch = ks * 4 + q16;
                av[i] = *(const h8*)&As[row * 64 + ((ch ^ (row & 7)) << 3)];
            }
#pragma unroll
            for (int j = 0; j < 4; j++) {
                int row = wc + j * 16 + l16;
                int ch = ks * 4 + q16;
                bv[j] = *(const h8*)&Bs[row * 64 + ((ch ^ (row & 7)) << 3)];
            }
#pragma unroll
            for (int i = 0; i < 4; i++)
#pragma unroll
                for (int j = 0; j < 4; j++)
                    acc[i][j] = MFMA16(av[i], bv[j], acc[i][j]);
        }
        __syncthreads();
    }
#pragma unroll
    for (int i = 0; i < 4; i++) {
        size_t r0 = m0 + wr + i * 16 + q16 * 4;
#pragma unroll
        for (int j = 0; j < 4; j++) {
            size_t c = n0 + wc + j * 16 + l16;
#pragma unroll
            for (int r = 0; r < 4; r++)
                C[(r0 + r) * N + c] = (h_t)(acc[i][j][r] * oscale);
        }
    }
}

// ---------------- fused T / V'' projections (1024 blocks) -------------------------
// blocks 0..511:  T  = S2h @ Wkq^T  (log2e-scaled scores)  [16384][512], K=512
// blocks 512..1023: Vt = (S1h @ Wvot^T + bo) stored transposed [b][d][n]
__global__ __launch_bounds__(256) void k_proj2(const h_t* __restrict__ S2h,
                                               const h_t* __restrict__ S1h,
                                               const h_t* __restrict__ Wkq,
                                               const h_t* __restrict__ Wvot,
                                               const float* __restrict__ bo,
                                               h_t* __restrict__ T,
                                               h_t* __restrict__ Vt) {
    __shared__ h_t As[128 * 64];
    __shared__ h_t Bs[128 * 64];
    int t = threadIdx.x, w = t >> 6, lane = t & 63;
    int q16 = lane >> 4, l16 = lane & 15;
    int id = blockIdx.x;
    int mode = id >> 9;
    id &= 511;
    const h_t* A = mode ? S1h : S2h;
    const h_t* Bt = mode ? Wvot : Wkq;
    size_t m0 = (size_t)(id >> 2) * 128, n0 = (size_t)(id & 3) * 128;
    const int K = 512;
    int wr = (w >> 1) * 64, wc = (w & 1) * 64;
    f4 acc[4][4] = {};

    for (int k0 = 0; k0 < K; k0 += 64) {
#pragma unroll
        for (int j = 0; j < 4; j++) {
            int q = w * 4 + j;
            int row = q * 8 + (lane >> 3);
            int ks = (((lane & 7) ^ (row & 7)) << 3);
            gl2lds16(A + (m0 + row) * K + k0 + ks, &As[q * 512]);
            gl2lds16(Bt + (n0 + row) * K + k0 + ks, &Bs[q * 512]);
        }
        __syncthreads();
#pragma unroll
        for (int ks = 0; ks < 2; ks++) {
            h8 av[4], bv[4];
#pragma unroll
            for (int i = 0; i < 4; i++) {
                int row = wr + i * 16 + l16;
                int ch = ks * 4 + q16;
                av[i] = *(const h8*)&As[row * 64 + ((ch ^ (row & 7)) << 3)];
            }
#pragma unroll
            for (int j = 0; j < 4; j++) {
                int row = wc + j * 16 + l16;
                int ch = ks * 4 + q16;
                bv[j] = *(const h8*)&Bs[row * 64 + ((ch ^ (row & 7)) << 3)];
            }
#pragma unroll
            for (int i = 0; i < 4; i++)
#pragma unroll
                for (int j = 0; j < 4; j++)
                    acc[i][j] = MFMA16(av[i], bv[j], acc[i][j]);
        }
        __syncthreads();
    }
    if (mode == 0) {
#pragma unroll
        for (int i = 0; i < 4; i++) {
            size_t r0 = m0 + wr + i * 16 + q16 * 4;
#pragma unroll
            for (int j = 0; j < 4; j++) {
                size_t c = n0 + wc + j * 16 + l16;
#pragma unroll
                for (int r = 0; r < 4; r++)
                    T[(r0 + r) * 512 + c] = (h_t)acc[i][j][r];
            }
        }
    } else {
#pragma unroll
        for (int i = 0; i < 4; i++) {
            size_t gm = m0 + wr + i * 16 + q16 * 4;
            size_t b = gm >> 11;
            size_t n = gm & 2047;
#pragma unroll
            for (int j = 0; j < 4; j++) {
                size_t d = n0 + wc + j * 16 + l16;
                float bias = bo[d];
                h4 hv = {(h_t)(acc[i][j][0] + bias), (h_t)(acc[i][j][1] + bias),
                         (h_t)(acc[i][j][2] + bias), (h_t)(acc[i][j][3] + bias)};
                *(h4*)&Vt[(b * 512 + d) * 2048 + n] = hv;
            }
        }
    }
}

// ---------------- pass 1: S-tile GEMM (K=512) + local stats + P (exp2) ------------
// grid (qt 16, kt 16, b 8) = 2048 blocks, 256 thr. S' = T @ S1h^T (log2 domain).
__global__ __launch_bounds__(256) void k_qk(const h_t* __restrict__ T,
                                            const h_t* __restrict__ S1h,
                                            h_t* __restrict__ P,
                                            float2* __restrict__ Mkt) {
    __shared__ h_t sm[16384];       // As(8192) + Bs(8192); reused as P-stage
    __shared__ float pmx[2][128], psm[2][128];
    h_t* As = sm;
    h_t* Bs = sm + 8192;
    int t = threadIdx.x, w = t >> 6, lane = t & 63;
    int q16 = lane >> 4, l16 = lane & 15;
    int qt = blockIdx.x, kt = blockIdx.y, b = blockIdx.z;
    const h_t* A = T + ((size_t)b * 2048 + qt * 128) * 512;
    const h_t* Bt = S1h + ((size_t)b * 2048 + kt * 128) * 512;
    int wr = (w >> 1) * 64, wc = (w & 1) * 64;
    f4 acc[4][4] = {};

    for (int k0 = 0; k0 < 512; k0 += 64) {
#pragma unroll
        for (int j = 0; j < 4; j++) {
            int q = w * 4 + j;
            int row = q * 8 + (lane >> 3);
            int ks = (((lane & 7) ^ (row & 7)) << 3);
            gl2lds16(A + (size_t)row * 512 + k0 + ks, &As[q * 512]);
            gl2lds16(Bt + (size_t)row * 512 + k0 + ks, &Bs[q * 512]);
        }
        __syncthreads();
#pragma unroll
        for (int ks = 0; ks < 2; ks++) {
            h8 av[4], bv[4];
#pragma unroll
            for (int i = 0; i < 4; i++) {
                int row = wr + i * 16 + l16;
                int ch = ks * 4 + q16;
                av[i] = *(const h8*)&As[row * 64 + ((ch ^ (row & 7)) << 3)];
            }
#pragma unroll
            for (int j = 0; j < 4; j++) {
                int row = wc + j * 16 + l16;
                int ch = ks * 4 + q16;
                bv[j] = *(const h8*)&Bs[row * 64 + ((ch ^ (row & 7)) << 3)];
            }
#pragma unroll
            for (int i = 0; i < 4; i++)
#pragma unroll
                for (int j = 0; j < 4; j++)
                    acc[i][j] = MFMA16(av[i], bv[j], acc[i][j]);
        }
        __syncthreads();
    }
    // ---- tile-local stats (log2 domain); e stored back into acc ----
    float lm[4][4], ls[4][4];
#pragma unroll
    for (int i = 0; i < 4; i++)
#pragma unroll
        for (int r = 0; r < 4; r++) {
            float m = acc[i][0][r];
#pragma unroll
            for (int j = 1; j < 4; j++) m = fmaxf(m, acc[i][j][r]);
            lm[i][r] = m;
        }
#pragma unroll
    for (int msk = 1; msk <= 8; msk <<= 1)
#pragma unroll
        for (int i = 0; i < 4; i++)
#pragma unroll
            for (int r = 0; r < 4; r++)
                lm[i][r] = fmaxf(lm[i][r], __shfl_xor(lm[i][r], msk, 64));
#pragma unroll
    for (int i = 0; i < 4; i++)
#pragma unroll
        for (int r = 0; r < 4; r++) {
            float s = 0.f;
#pragma unroll
            for (int j = 0; j < 4; j++) {
                float e = exp2f(acc[i][j][r] - lm[i][r]);
                acc[i][j][r] = e;        // keep e; rescale at write
                s += e;
            }
            ls[i][r] = s;
        }
#pragma unroll
    for (int msk = 1; msk <= 8; msk <<= 1)
#pragma unroll
        for (int i = 0; i < 4; i++)
#pragma unroll
            for (int r = 0; r < 4; r++)
                ls[i][r] += __shfl_xor(ls[i][r], msk, 64);
    if (l16 == 0) {
#pragma unroll
        for (int i = 0; i < 4; i++)
#pragma unroll
            for (int r = 0; r < 4; r++) {
                pmx[w & 1][wr + i * 16 + q16 * 4 + r] = lm[i][r];
                psm[w & 1][wr + i * 16 + q16 * 4 + r] = ls[i][r];
            }
    }
    __syncthreads();
    // pairwise combine; lm becomes the P rescale factor exp2(lm_wave - M_tile)
#pragma unroll
    for (int i = 0; i < 4; i++)
#pragma unroll
        for (int r = 0; r < 4; r++) {
            int row = wr + i * 16 + q16 * 4 + r;
            float om = pmx[(w & 1) ^ 1][row];
            float os = psm[(w & 1) ^ 1][row];
            float M = fmaxf(lm[i][r], om);
            float sc = exp2f(lm[i][r] - M);
            float L = ls[i][r] * sc + os * exp2f(om - M);
            if ((w & 1) == 0 && l16 == 0)
                Mkt[((size_t)b * 16 + kt) * 2048 + qt * 128 + row] = make_float2(M, L);
            lm[i][r] = sc;
        }
    // ---- P tile -> LDS fp16 (As/Bs dead), then coalesced global store ----
#pragma unroll
    for (int i = 0; i < 4; i++)
#pragma unroll
        for (int j = 0; j < 4; j++)
#pragma unroll
            for (int r = 0; r < 4; r++)
                sm[(wr + i * 16 + q16 * 4 + r) * 128 + wc + j * 16 + l16] =
                    (h_t)(acc[i][j][r] * lm[i][r]);
    __syncthreads();
    size_t Pbase = ((size_t)b * 2048 + qt * 128) * 2048 + (size_t)kt * 128;
#pragma unroll
    for (int p = 0; p < 8; p++) {
        int row = p * 16 + (t >> 4);
        int c8 = (t & 15) * 8;
        *(h8*)(P + Pbase + (size_t)row * 2048 + c8) = *(const h8*)&sm[row * 128 + c8];
    }
}

// ---------------- pass 1.5: final stats + fp16 delta table ----------------
__global__ __launch_bounds__(256) void k_stats(const float2* __restrict__ Mkt,
                                               float2* __restrict__ MF,
                                               h_t* __restrict__ Dkt) {
    int r = blockIdx.x * 256 + threadIdx.x;  // 0..16383
    int b = r >> 11, rowl = r & 2047;
    float2 v[16];
    float m = -1e30f;
#pragma unroll
    for (int kt = 0; kt < 16; kt++) {
        v[kt] = Mkt[((size_t)b * 16 + kt) * 2048 + rowl];
        m = fmaxf(m, v[kt].x);
    }
    float l = 0.f;
#pragma unroll
    for (int kt = 0; kt < 16; kt++) {
        float d = exp2f(v[kt].x - m);
        l += v[kt].y * d;
        Dkt[((size_t)b * 16 + kt) * 2048 + rowl] = (h_t)d;
    }
    MF[(size_t)b * 2048 + rowl] = make_float2(m, 1.f / l);
}

// ---------------- pass 2: O = sum_kt (P_kt * Dkt) @ V'', x 1/l_fin ----------------
// grid (rt 32, dt 4, b 8) = 1024 blocks, 256 thr. Zero transcendentals in loop.
__global__ __launch_bounds__(256) void k_pv(const h_t* __restrict__ P,
                                            const h_t* __restrict__ Vt,
                                            const h_t* __restrict__ Dkt,
                                            const float2* __restrict__ MF,
                                            float* __restrict__ Out) {
    __shared__ h_t As[64 * 64];     // P-tile 8 KB (delta-scaled)
    __shared__ h_t Bs[128 * 64];    // V-tile 16 KB
    int t = threadIdx.x, w = t >> 6, lane = t & 63;
    int q16 = lane >> 4, l16 = lane & 15;
    int rt = blockIdx.x, dt = blockIdx.y, b = blockIdx.z;
    int rg = w >> 1, dg = w & 1;
    int sr = t >> 3, sc = t & 7;    // staging coords: row / col octet
    const h_t* Pb = P + ((size_t)b * 2048 + rt * 64) * 2048;
    const h_t* Vb = Vt + ((size_t)b * 512 + dt * 128) * 2048;
    f4 acc[2][4] = {};

    for (int kt = 0; kt < 16; kt++) {
        h_t d0 = Dkt[((size_t)b * 16 + kt) * 2048 + rt * 64 + sr];
        h_t d1 = Dkt[((size_t)b * 16 + kt) * 2048 + rt * 64 + 32 + sr];
#pragma unroll
        for (int h = 0; h < 2; h++) {
            int k0 = kt * 128 + h * 64;
#pragma unroll
            for (int p = 0; p < 2; p++) {
                int r_ = p * 32 + sr;
                h_t dh = p ? d1 : d0;
                h8 dv = {dh, dh, dh, dh, dh, dh, dh, dh};
                h8 v = *(const h8*)(Pb + (size_t)r_ * 2048 + k0 + sc * 8);
                v = v * dv;
                *(h8*)&As[r_ * 64 + ((sc ^ (r_ & 7)) << 3)] = v;
            }
#pragma unroll
            for (int j = 0; j < 4; j++) {
                int q = w * 4 + j;
                int row = q * 8 + (lane >> 3);
                int ks = (((lane & 7) ^ (row & 7)) << 3);
                gl2lds16(Vb + (size_t)row * 2048 + k0 + ks, &Bs[q * 512]);
            }
            __syncthreads();
#pragma unroll
            for (int ks = 0; ks < 2; ks++) {
                int ch = ks * 4 + q16;
                h8 av[2], bv[4];
#pragma unroll
                for (int i = 0; i < 2; i++) {
                    int row = rg * 32 + i * 16 + l16;
                    av[i] = *(const h8*)&As[row * 64 + ((ch ^ (row & 7)) << 3)];
                }
#pragma unroll
                for (int j = 0; j < 4; j++) {
                    int dr = dg * 64 + j * 16 + l16;
                    bv[j] = *(const h8*)&Bs[dr * 64 + ((ch ^ (dr & 7)) << 3)];
                }
#pragma unroll
                for (int i = 0; i < 2; i++)
#pragma unroll
                    for (int j = 0; j < 4; j++)
                        acc[i][j] = MFMA16(av[i], bv[j], acc[i][j]);
            }
            __syncthreads();
        }
    }
#pragma unroll
    for (int i = 0; i < 2; i++)
#pragma unroll
        for (int rr = 0; rr < 4; rr++) {
            int row = rg * 32 + i * 16 + q16 * 4 + rr;
            float linv = MF[(size_t)b * 2048 + rt * 64 + row].y;
#pragma unroll
            for (int j = 0; j < 4; j++) {
                int d = dt * 128 + dg * 64 + j * 16 + l16;
                Out[((size_t)b * 2048 + rt * 64 + row) * 512 + d] =
                    acc[i][j][rr] * linv;
            }
        }
}

// ---------------- host ----------------
extern "C" void kernel_launch(void* const* d_in, const int* in_sizes, int n_in,
                              void* d_out, int out_size, void* d_ws, size_t ws_size,
                              hipStream_t stream) {
    const float* S1 = (const float*)d_in[0];
    const float* S2 = (const float*)d_in[1];
    const float* Wq = (const float*)d_in[2];
    const float* Wk = (const float*)d_in[3];
    const float* Wv = (const float*)d_in[4];
    const float* Wo = (const float*)d_in[5];
    const float* bo = (const float*)d_in[6];
    float* Out = (float*)d_out;

    char* ws = (char*)d_ws;
    // persistent through attention:
    h_t* S1h  = (h_t*)(ws);                  // 16 MB (live through k_qk)
    h_t* T    = (h_t*)(ws + 16777216);       // 16 MB (live through k_qk)
    h_t* Vt   = (h_t*)(ws + 33554432);       // 16 MB (live through k_pv)
    h_t* P    = (h_t*)(ws + 50331648);       // 64 MB [8][2048][2048] -> 117,440,512
    float2* Mkt = (float2*)(ws + 117440512); // 2 MB [8][16][2048] -> 119,537,664
    // aliases inside P (all dead before k_qk writes P):
    h_t* S2h  = (h_t*)(ws + 50331648);       // 16 MB (dead after k_proj2)
    h_t* Wqh  = (h_t*)(ws + 67108864);       // 1 MB
    h_t* Wkh  = (h_t*)(ws + 68157440);       // 1 MB
    h_t* Wvh  = (h_t*)(ws + 69206016);       // 1 MB
    h_t* Wot  = (h_t*)(ws + 70254592);       // 1 MB
    h_t* Wkq  = (h_t*)(ws + 71303168);       // 0.5 MB
    h_t* Wvot = (h_t*)(ws + 71827456);       // 0.5 MB
    // aliases inside S1h (written by k_stats, after S1h is dead):
    h_t* Dkt  = (h_t*)(ws);                  // 512 KB [8][16][2048]
    float2* MF = (float2*)(ws + 524288);     // 128 KB [8][2048]

    k_cast5<<<17920, 256, 0, stream>>>(S1, S2, Wq, Wk, Wv, S1h, S2h, Wqh, Wkh, Wvh);
    k_transpose_o<<<dim3(16, 32), 256, 0, stream>>>(Wo, Wot);
    k_wpre<<<32, 256, 0, stream>>>(Wqh, Wkh, Wot, Wvh, Wkq, Wvot);
    k_proj2<<<1024, 256, 0, stream>>>(S2h, S1h, Wkq, Wvot, bo, T, Vt);
    k_qk<<<dim3(16, 16, 8), 256, 0, stream>>>(T, S1h, P, Mkt);
    k_stats<<<64, 256, 0, stream>>>(Mkt, MF, Dkt);
    k_pv<<<dim3(32, 4, 8), 256, 0, stream>>>(P, Vt, Dkt, MF, Out);
}

// Round 8
// 284.539 us; speedup vs baseline: 1.7888x; 1.0305x over previous
//
#include <hip/hip_runtime.h>

// CrossAttention: out = softmax((S2 Wq)(S1 Wk)^T) (S1 Wv) Wo + bo
// R14 = R13 (Wkq fold, exp2 domain, single-P two-pass attention) with k_qk
// computing the S-tile TRANSPOSED (A = S1 keys, B = T qrows). Reduction axis
// (keys) becomes mostly lane-local: 128 shuffle ops -> 16, per-lane row state
// 16 -> 4, P-stage 64 scalar ds_write_u16 -> 16 ds_write_b64 (h4). P-stage
// stride 136 h_t (272B, 16B-aligned rows). Global P layout, k_pv, k_stats,
// projection kernels unchanged. Math identical to R13 (absmax guard 0.0117).

typedef _Float16 h_t;
typedef _Float16 h8 __attribute__((ext_vector_type(8)));
typedef _Float16 h4 __attribute__((ext_vector_type(4)));
typedef float f4 __attribute__((ext_vector_type(4)));

#define MFMA16(a, b, c) __builtin_amdgcn_mfma_f32_16x16x32_f16(a, b, c, 0, 0, 0)

typedef const __attribute__((address_space(1))) void* gas_t;
typedef __attribute__((address_space(3))) void* las_t;

__device__ __forceinline__ void gl2lds16(const void* g, void* l) {
    __builtin_amdgcn_global_load_lds((gas_t)g, (las_t)l, 16, 0, 0);
}

// ---------------- merged cast fp32 -> fp16: S1, S2, Wq, Wk, Wv ----------------
__global__ __launch_bounds__(256) void k_cast5(const float* __restrict__ S1,
                                               const float* __restrict__ S2,
                                               const float* __restrict__ Wq,
                                               const float* __restrict__ Wk,
                                               const float* __restrict__ Wv,
                                               h_t* __restrict__ S1h,
                                               h_t* __restrict__ S2h,
                                               h_t* __restrict__ Wqh,
                                               h_t* __restrict__ Wkh,
                                               h_t* __restrict__ Wvh) {
    long i = (long)blockIdx.x * 256 + threadIdx.x;  // f4 index
    const long n = 2097152;                          // S1/S2 f4 count
    const long wn = 131072;                          // weight f4 count
    const float* src;
    h_t* dst;
    long off;
    if (i < n) { src = S1; dst = S1h; off = i; }
    else if (i < 2 * n) { src = S2; dst = S2h; off = i - n; }
    else if (i < 2 * n + wn) { src = Wq; dst = Wqh; off = i - 2 * n; }
    else if (i < 2 * n + 2 * wn) { src = Wk; dst = Wkh; off = i - 2 * n - wn; }
    else { src = Wv; dst = Wvh; off = i - 2 * n - 2 * wn; }
    float4 v = *((const float4*)src + off);
    h4 h = {(h_t)v.x, (h_t)v.y, (h_t)v.z, (h_t)v.w};
    *((h4*)dst + off) = h;
}

// ---------------- transpose+cast: Wo [1024][512] -> Wot [512][1024] f16 -----------
__global__ __launch_bounds__(256) void k_transpose_o(const float* __restrict__ Wo,
                                                     h_t* __restrict__ Wot) {
    const int K = 1024, N = 512;
    int kb = blockIdx.y * 32, nb = blockIdx.x * 32;
    __shared__ float tile[32][33];
    int x = threadIdx.x & 31, y = threadIdx.x >> 5;
#pragma unroll
    for (int j = 0; j < 4; j++)
        tile[y + j * 8][x] = Wo[(size_t)(kb + y + j * 8) * N + nb + x];
    __syncthreads();
#pragma unroll
    for (int j = 0; j < 4; j++)
        Wot[(size_t)(nb + y + j * 8) * K + kb + x] = (h_t)tile[x][y + j * 8];
}

// ---------------- fused weight-fold GEMMs: Wkq (x log2e) and Wvot ----------------
__global__ __launch_bounds__(256) void k_wpre(const h_t* __restrict__ Wqh,
                                              const h_t* __restrict__ Wkh,
                                              const h_t* __restrict__ Wot,
                                              const h_t* __restrict__ Wvh,
                                              h_t* __restrict__ Wkq,
                                              h_t* __restrict__ Wvot) {
    __shared__ h_t As[128 * 64];
    __shared__ h_t Bs[128 * 64];
    int t = threadIdx.x, w = t >> 6, lane = t & 63;
    int q16 = lane >> 4, l16 = lane & 15;
    int id = blockIdx.x;
    const h_t* A;
    const h_t* Bt;
    h_t* C;
    float oscale;
    if (id < 16) { A = Wkh; Bt = Wqh; C = Wkq; oscale = 1.44269504f; }
    else { id -= 16; A = Wot; Bt = Wvh; C = Wvot; oscale = 1.0f; }
    size_t m0 = (size_t)(id >> 2) * 128, n0 = (size_t)(id & 3) * 128;
    const int K = 1024, N = 512;
    int wr = (w >> 1) * 64, wc = (w & 1) * 64;
    f4 acc[4][4] = {};

    for (int k0 = 0; k0 < K; k0 += 64) {
#pragma unroll
        for (int j = 0; j < 4; j++) {
            int q = w * 4 + j;
            int row = q * 8 + (lane >> 3);
            int ks = (((lane & 7) ^ (row & 7)) << 3);
            gl2lds16(A + (m0 + row) * K + k0 + ks, &As[q * 512]);
            gl2lds16(Bt + (n0 + row) * K + k0 + ks, &Bs[q * 512]);
        }
        __syncthreads();
#pragma unroll
        for (int ks = 0; ks < 2; ks++) {
            h8 av[4], bv[4];
#pragma unroll
            for (int i = 0; i < 4; i++) {
                int row = wr + i * 16 + l16;
                int ch = ks * 4 + q16;
                av[i] = *(const h8*)&As[row * 64 + ((ch ^ (row & 7)) << 3)];
            }
#pragma unroll
            for (int j = 0; j < 4; j++) {
                int row = wc + j * 16 + l16;
                int ch = ks * 4 + q16;
                bv[j] = *(const h8*)&Bs[row * 64 + ((ch ^ (row & 7)) << 3)];
            }
#pragma unroll
            for (int i = 0; i < 4; i++)
#pragma unroll
                for (int j = 0; j < 4; j++)
                    acc[i][j] = MFMA16(av[i], bv[j], acc[i][j]);
        }
        __syncthreads();
    }
#pragma unroll
    for (int i = 0; i < 4; i++) {
        size_t r0 = m0 + wr + i * 16 + q16 * 4;
#pragma unroll
        for (int j = 0; j < 4; j++) {
            size_t c = n0 + wc + j * 16 + l16;
#pragma unroll
            for (int r = 0; r < 4; r++)
                C[(r0 + r) * N + c] = (h_t)(acc[i][j][r] * oscale);
        }
    }
}

// ---------------- fused T / V'' projections (1024 blocks) -------------------------
__global__ __launch_bounds__(256) void k_proj2(const h_t* __restrict__ S2h,
                                               const h_t* __restrict__ S1h,
                                               const h_t* __restrict__ Wkq,
                                               const h_t* __restrict__ Wvot,
                                               const float* __restrict__ bo,
                                               h_t* __restrict__ T,
                                               h_t* __restrict__ Vt) {
    __shared__ h_t As[128 * 64];
    __shared__ h_t Bs[128 * 64];
    int t = threadIdx.x, w = t >> 6, lane = t & 63;
    int q16 = lane >> 4, l16 = lane & 15;
    int id = blockIdx.x;
    int mode = id >> 9;
    id &= 511;
    const h_t* A = mode ? S1h : S2h;
    const h_t* Bt = mode ? Wvot : Wkq;
    size_t m0 = (size_t)(id >> 2) * 128, n0 = (size_t)(id & 3) * 128;
    const int K = 512;
    int wr = (w >> 1) * 64, wc = (w & 1) * 64;
    f4 acc[4][4] = {};

    for (int k0 = 0; k0 < K; k0 += 64) {
#pragma unroll
        for (int j = 0; j < 4; j++) {
            int q = w * 4 + j;
            int row = q * 8 + (lane >> 3);
            int ks = (((lane & 7) ^ (row & 7)) << 3);
            gl2lds16(A + (m0 + row) * K + k0 + ks, &As[q * 512]);
            gl2lds16(Bt + (n0 + row) * K + k0 + ks, &Bs[q * 512]);
        }
        __syncthreads();
#pragma unroll
        for (int ks = 0; ks < 2; ks++) {
            h8 av[4], bv[4];
#pragma unroll
            for (int i = 0; i < 4; i++) {
                int row = wr + i * 16 + l16;
                int ch = ks * 4 + q16;
                av[i] = *(const h8*)&As[row * 64 + ((ch ^ (row & 7)) << 3)];
            }
#pragma unroll
            for (int j = 0; j < 4; j++) {
                int row = wc + j * 16 + l16;
                int ch = ks * 4 + q16;
                bv[j] = *(const h8*)&Bs[row * 64 + ((ch ^ (row & 7)) << 3)];
            }
#pragma unroll
            for (int i = 0; i < 4; i++)
#pragma unroll
                for (int j = 0; j < 4; j++)
                    acc[i][j] = MFMA16(av[i], bv[j], acc[i][j]);
        }
        __syncthreads();
    }
    if (mode == 0) {
#pragma unroll
        for (int i = 0; i < 4; i++) {
            size_t r0 = m0 + wr + i * 16 + q16 * 4;
#pragma unroll
            for (int j = 0; j < 4; j++) {
                size_t c = n0 + wc + j * 16 + l16;
#pragma unroll
                for (int r = 0; r < 4; r++)
                    T[(r0 + r) * 512 + c] = (h_t)acc[i][j][r];
            }
        }
    } else {
#pragma unroll
        for (int i = 0; i < 4; i++) {
            size_t gm = m0 + wr + i * 16 + q16 * 4;
            size_t b = gm >> 11;
            size_t n = gm & 2047;
#pragma unroll
            for (int j = 0; j < 4; j++) {
                size_t d = n0 + wc + j * 16 + l16;
                float bias = bo[d];
                h4 hv = {(h_t)(acc[i][j][0] + bias), (h_t)(acc[i][j][1] + bias),
                         (h_t)(acc[i][j][2] + bias), (h_t)(acc[i][j][3] + bias)};
                *(h4*)&Vt[(b * 512 + d) * 2048 + n] = hv;
            }
        }
    }
}

// ---------------- pass 1: S^T-tile GEMM (K=512) + local stats + P (exp2) ----------
// grid (qt 16, kt 16, b 8) = 2048 blocks, 256 thr. Computes St[key][qrow] =
// S1h-tile @ T-tile^T (log2 domain). Keys = MFMA rows -> per lane, per qrow-
// frag j, 16 key values in-register; cross-lane only over q16 (masks 16,32).
__global__ __launch_bounds__(256) void k_qk(const h_t* __restrict__ T,
                                            const h_t* __restrict__ S1h,
                                            h_t* __restrict__ P,
                                            float2* __restrict__ Mkt) {
    __shared__ h_t sm[18432];       // 36864B: GEMM As/Bs (32KB) | P-stage 128x136
    h_t* As = sm;                   // keys tile (S1h rows)
    h_t* Bs = sm + 8192;            // qrow tile (T rows)
    float* pmx = (float*)(sm + 17408);   // [2][128] wave-pair partial max
    float* psm = (float*)(sm + 17920);   // [2][128] wave-pair partial sum
    int t = threadIdx.x, w = t >> 6, lane = t & 63;
    int q16 = lane >> 4, l16 = lane & 15;
    int qt = blockIdx.x, kt = blockIdx.y, b = blockIdx.z;
    const h_t* A = S1h + ((size_t)b * 2048 + kt * 128) * 512;   // keys
    const h_t* Bt = T + ((size_t)b * 2048 + qt * 128) * 512;    // qrows
    int wr = (w >> 1) * 64, wc = (w & 1) * 64;  // wr = key-half, wc = qrow-half
    f4 acc[4][4] = {};

    for (int k0 = 0; k0 < 512; k0 += 64) {
#pragma unroll
        for (int j = 0; j < 4; j++) {
            int q = w * 4 + j;
            int row = q * 8 + (lane >> 3);
            int ks = (((lane & 7) ^ (row & 7)) << 3);
            gl2lds16(A + (size_t)row * 512 + k0 + ks, &As[q * 512]);
            gl2lds16(Bt + (size_t)row * 512 + k0 + ks, &Bs[q * 512]);
        }
        __syncthreads();
#pragma unroll
        for (int ks = 0; ks < 2; ks++) {
            h8 av[4], bv[4];
#pragma unroll
            for (int i = 0; i < 4; i++) {
                int row = wr + i * 16 + l16;
                int ch = ks * 4 + q16;
                av[i] = *(const h8*)&As[row * 64 + ((ch ^ (row & 7)) << 3)];
            }
#pragma unroll
            for (int j = 0; j < 4; j++) {
                int row = wc + j * 16 + l16;
                int ch = ks * 4 + q16;
                bv[j] = *(const h8*)&Bs[row * 64 + ((ch ^ (row & 7)) << 3)];
            }
#pragma unroll
            for (int i = 0; i < 4; i++)
#pragma unroll
                for (int j = 0; j < 4; j++)
                    acc[i][j] = MFMA16(av[i], bv[j], acc[i][j]);
        }
        __syncthreads();
    }
    // acc[i][j][r]: key = wr + i*16 + q16*4 + r, qrow = wc + j*16 + l16.
    // ---- per-qrow stats: in-lane over (i,r), cross-lane over q16 only ----
    float lm[4], ls[4], sc[4];
#pragma unroll
    for (int j = 0; j < 4; j++) {
        float m = acc[0][j][0];
#pragma unroll
        for (int i = 0; i < 4; i++)
#pragma unroll
            for (int r = 0; r < 4; r++) m = fmaxf(m, acc[i][j][r]);
        lm[j] = m;
    }
#pragma unroll
    for (int msk = 16; msk <= 32; msk <<= 1)
#pragma unroll
        for (int j = 0; j < 4; j++)
            lm[j] = fmaxf(lm[j], __shfl_xor(lm[j], msk, 64));
#pragma unroll
    for (int j = 0; j < 4; j++) {
        float s = 0.f;
#pragma unroll
        for (int i = 0; i < 4; i++)
#pragma unroll
            for (int r = 0; r < 4; r++) {
                float e = exp2f(acc[i][j][r] - lm[j]);
                acc[i][j][r] = e;       // keep e; rescale by sc at P-write
                s += e;
            }
        ls[j] = s;
    }
#pragma unroll
    for (int msk = 16; msk <= 32; msk <<= 1)
#pragma unroll
        for (int j = 0; j < 4; j++) ls[j] += __shfl_xor(ls[j], msk, 64);
    if (q16 == 0) {
#pragma unroll
        for (int j = 0; j < 4; j++) {
            pmx[(w >> 1) * 128 + wc + j * 16 + l16] = lm[j];
            psm[(w >> 1) * 128 + wc + j * 16 + l16] = ls[j];
        }
    }
    __syncthreads();   // partials visible (also: all GEMM reads of As/Bs done)
    // ---- combine the two key-halves; sc = exp2(lm_wave - M_tile) ----
#pragma unroll
    for (int j = 0; j < 4; j++) {
        int row = wc + j * 16 + l16;
        float om = pmx[((w >> 1) ^ 1) * 128 + row];
        float os = psm[((w >> 1) ^ 1) * 128 + row];
        float M = fmaxf(lm[j], om);
        float s = exp2f(lm[j] - M);
        float L = ls[j] * s + os * exp2f(om - M);
        sc[j] = s;
        if ((w >> 1) == 0 && q16 == 0)
            Mkt[((size_t)b * 16 + kt) * 2048 + qt * 128 + row] = make_float2(M, L);
    }
    // ---- P-stage: sm[qrow][key], stride 136 (272B rows, 16B-aligned) ----
#pragma unroll
    for (int j = 0; j < 4; j++)
#pragma unroll
        for (int i = 0; i < 4; i++) {
            h4 hv = {(h_t)(acc[i][j][0] * sc[j]), (h_t)(acc[i][j][1] * sc[j]),
                     (h_t)(acc[i][j][2] * sc[j]), (h_t)(acc[i][j][3] * sc[j])};
            *(h4*)&sm[(wc + j * 16 + l16) * 136 + wr + i * 16 + q16 * 4] = hv;
        }
    __syncthreads();
    // ---- coalesced global store: P[qrow][key] row-major ----
    size_t Pbase = ((size_t)b * 2048 + qt * 128) * 2048 + (size_t)kt * 128;
#pragma unroll
    for (int p = 0; p < 8; p++) {
        int row = p * 16 + (t >> 4);
        int c8 = (t & 15) * 8;
        *(h8*)(P + Pbase + (size_t)row * 2048 + c8) = *(const h8*)&sm[row * 136 + c8];
    }
}

// ---------------- pass 1.5: final stats + fp16 delta table ----------------
__global__ __launch_bounds__(256) void k_stats(const float2* __restrict__ Mkt,
                                               float2* __restrict__ MF,
                                               h_t* __restrict__ Dkt) {
    int r = blockIdx.x * 256 + threadIdx.x;  // 0..16383
    int b = r >> 11, rowl = r & 2047;
    float2 v[16];
    float m = -1e30f;
#pragma unroll
    for (int kt = 0; kt < 16; kt++) {
        v[kt] = Mkt[((size_t)b * 16 + kt) * 2048 + rowl];
        m = fmaxf(m, v[kt].x);
    }
    float l = 0.f;
#pragma unroll
    for (int kt = 0; kt < 16; kt++) {
        float d = exp2f(v[kt].x - m);
        l += v[kt].y * d;
        Dkt[((size_t)b * 16 + kt) * 2048 + rowl] = (h_t)d;
    }
    MF[(size_t)b * 2048 + rowl] = make_float2(m, 1.f / l);
}

// ---------------- pass 2: O = sum_kt (P_kt * Dkt) @ V'', x 1/l_fin ----------------
__global__ __launch_bounds__(256) void k_pv(const h_t* __restrict__ P,
                                            const h_t* __restrict__ Vt,
                                            const h_t* __restrict__ Dkt,
                                            const float2* __restrict__ MF,
                                            float* __restrict__ Out) {
    __shared__ h_t As[64 * 64];     // P-tile 8 KB (delta-scaled)
    __shared__ h_t Bs[128 * 64];    // V-tile 16 KB
    int t = threadIdx.x, w = t >> 6, lane = t & 63;
    int q16 = lane >> 4, l16 = lane & 15;
    int rt = blockIdx.x, dt = blockIdx.y, b = blockIdx.z;
    int rg = w >> 1, dg = w & 1;
    int sr = t >> 3, sc = t & 7;    // staging coords: row / col octet
    const h_t* Pb = P + ((size_t)b * 2048 + rt * 64) * 2048;
    const h_t* Vb = Vt + ((size_t)b * 512 + dt * 128) * 2048;
    f4 acc[2][4] = {};

    for (int kt = 0; kt < 16; kt++) {
        h_t d0 = Dkt[((size_t)b * 16 + kt) * 2048 + rt * 64 + sr];
        h_t d1 = Dkt[((size_t)b * 16 + kt) * 2048 + rt * 64 + 32 + sr];
#pragma unroll
        for (int h = 0; h < 2; h++) {
            int k0 = kt * 128 + h * 64;
#pragma unroll
            for (int p = 0; p < 2; p++) {
                int r_ = p * 32 + sr;
                h_t dh = p ? d1 : d0;
                h8 dv = {dh, dh, dh, dh, dh, dh, dh, dh};
                h8 v = *(const h8*)(Pb + (size_t)r_ * 2048 + k0 + sc * 8);
                v = v * dv;
                *(h8*)&As[r_ * 64 + ((sc ^ (r_ & 7)) << 3)] = v;
            }
#pragma unroll
            for (int j = 0; j < 4; j++) {
                int q = w * 4 + j;
                int row = q * 8 + (lane >> 3);
                int ks = (((lane & 7) ^ (row & 7)) << 3);
                gl2lds16(Vb + (size_t)row * 2048 + k0 + ks, &Bs[q * 512]);
            }
            __syncthreads();
#pragma unroll
            for (int ks = 0; ks < 2; ks++) {
                int ch = ks * 4 + q16;
                h8 av[2], bv[4];
#pragma unroll
                for (int i = 0; i < 2; i++) {
                    int row = rg * 32 + i * 16 + l16;
                    av[i] = *(const h8*)&As[row * 64 + ((ch ^ (row & 7)) << 3)];
                }
#pragma unroll
                for (int j = 0; j < 4; j++) {
                    int dr = dg * 64 + j * 16 + l16;
                    bv[j] = *(const h8*)&Bs[dr * 64 + ((ch ^ (dr & 7)) << 3)];
                }
#pragma unroll
                for (int i = 0; i < 2; i++)
#pragma unroll
                    for (int j = 0; j < 4; j++)
                        acc[i][j] = MFMA16(av[i], bv[j], acc[i][j]);
            }
            __syncthreads();
        }
    }
#pragma unroll
    for (int i = 0; i < 2; i++)
#pragma unroll
        for (int rr = 0; rr < 4; rr++) {
            int row = rg * 32 + i * 16 + q16 * 4 + rr;
            float linv = MF[(size_t)b * 2048 + rt * 64 + row].y;
#pragma unroll
            for (int j = 0; j < 4; j++) {
                int d = dt * 128 + dg * 64 + j * 16 + l16;
                Out[((size_t)b * 2048 + rt * 64 + row) * 512 + d] =
                    acc[i][j][rr] * linv;
            }
        }
}

// ---------------- host ----------------
extern "C" void kernel_launch(void* const* d_in, const int* in_sizes, int n_in,
                              void* d_out, int out_size, void* d_ws, size_t ws_size,
                              hipStream_t stream) {
    const float* S1 = (const float*)d_in[0];
    const float* S2 = (const float*)d_in[1];
    const float* Wq = (const float*)d_in[2];
    const float* Wk = (const float*)d_in[3];
    const float* Wv = (const float*)d_in[4];
    const float* Wo = (const float*)d_in[5];
    const float* bo = (const float*)d_in[6];
    float* Out = (float*)d_out;

    char* ws = (char*)d_ws;
    // persistent through attention:
    h_t* S1h  = (h_t*)(ws);                  // 16 MB (live through k_qk)
    h_t* T    = (h_t*)(ws + 16777216);       // 16 MB (live through k_qk)
    h_t* Vt   = (h_t*)(ws + 33554432);       // 16 MB (live through k_pv)
    h_t* P    = (h_t*)(ws + 50331648);       // 64 MB [8][2048][2048]
    float2* Mkt = (float2*)(ws + 117440512); // 2 MB [8][16][2048]
    // aliases inside P (all dead before k_qk writes P):
    h_t* S2h  = (h_t*)(ws + 50331648);       // 16 MB (dead after k_proj2)
    h_t* Wqh  = (h_t*)(ws + 67108864);       // 1 MB
    h_t* Wkh  = (h_t*)(ws + 68157440);       // 1 MB
    h_t* Wvh  = (h_t*)(ws + 69206016);       // 1 MB
    h_t* Wot  = (h_t*)(ws + 70254592);       // 1 MB
    h_t* Wkq  = (h_t*)(ws + 71303168);       // 0.5 MB
    h_t* Wvot = (h_t*)(ws + 71827456);       // 0.5 MB
    // aliases inside S1h (written by k_stats, after S1h is dead):
    h_t* Dkt  = (h_t*)(ws);                  // 512 KB [8][16][2048]
    float2* MF = (float2*)(ws + 524288);     // 128 KB [8][2048]

    k_cast5<<<17920, 256, 0, stream>>>(S1, S2, Wq, Wk, Wv, S1h, S2h, Wqh, Wkh, Wvh);
    k_transpose_o<<<dim3(16, 32), 256, 0, stream>>>(Wo, Wot);
    k_wpre<<<32, 256, 0, stream>>>(Wqh, Wkh, Wot, Wvh, Wkq, Wvot);
    k_proj2<<<1024, 256, 0, stream>>>(S2h, S1h, Wkq, Wvot, bo, T, Vt);
    k_qk<<<dim3(16, 16, 8), 256, 0, stream>>>(T, S1h, P, Mkt);
    k_stats<<<64, 256, 0, stream>>>(Mkt, MF, Dkt);
    k_pv<<<dim3(32, 4, 8), 256, 0, stream>>>(P, Vt, Dkt, MF, Out);
}

// Round 9
// 280.379 us; speedup vs baseline: 1.8153x; 1.0148x over previous
//
#include <hip/hip_runtime.h>

// CrossAttention: out = softmax((S2 Wq)(S1 Wk)^T) (S1 Wv) Wo + bo
// R15 = R14 (Wkq fold, exp2 domain, swapped-operand k_qk, single-P two-pass)
// with dispatch-count and k_pv upgrades:
//  - k_prep: cast5 + transpose_o merged (one launch).
//  - k_pv: tile 64x128 -> 128x128 (k_gemm wave layout, 0.5 LDS-reads/MFMA,
//    V-stage per-MFMA traffic halved); k_stats INLINED as a per-block
//    prologue (Mkt -> m_fin, 1/l, 16 kt deltas in LDS). Dkt/MF buffers gone.
//  - pipeline: k_prep -> k_wpre -> k_proj2 -> k_qk -> k_pv (5 dispatches).

typedef _Float16 h_t;
typedef _Float16 h8 __attribute__((ext_vector_type(8)));
typedef _Float16 h4 __attribute__((ext_vector_type(4)));
typedef float f4 __attribute__((ext_vector_type(4)));

#define MFMA16(a, b, c) __builtin_amdgcn_mfma_f32_16x16x32_f16(a, b, c, 0, 0, 0)

typedef const __attribute__((address_space(1))) void* gas_t;
typedef __attribute__((address_space(3))) void* las_t;

__device__ __forceinline__ void gl2lds16(const void* g, void* l) {
    __builtin_amdgcn_global_load_lds((gas_t)g, (las_t)l, 16, 0, 0);
}

// ---------------- merged prep: cast S1,S2,Wq,Wk,Wv + transpose Wo ----------------
// blocks 0..17919: fp32->fp16 casts (f4 granularity).
// blocks 17920..18431: Wo [1024][512] -> Wot [512][1024] (32x32 tiles).
__global__ __launch_bounds__(256) void k_prep(const float* __restrict__ S1,
                                              const float* __restrict__ S2,
                                              const float* __restrict__ Wq,
                                              const float* __restrict__ Wk,
                                              const float* __restrict__ Wv,
                                              const float* __restrict__ Wo,
                                              h_t* __restrict__ S1h,
                                              h_t* __restrict__ S2h,
                                              h_t* __restrict__ Wqh,
                                              h_t* __restrict__ Wkh,
                                              h_t* __restrict__ Wvh,
                                              h_t* __restrict__ Wot) {
    __shared__ float tile[32][33];
    long bid = blockIdx.x;
    if (bid < 17920) {
        long i = bid * 256 + threadIdx.x;            // f4 index
        const long n = 2097152;                       // S1/S2 f4 count
        const long wn = 131072;                       // weight f4 count
        const float* src;
        h_t* dst;
        long off;
        if (i < n) { src = S1; dst = S1h; off = i; }
        else if (i < 2 * n) { src = S2; dst = S2h; off = i - n; }
        else if (i < 2 * n + wn) { src = Wq; dst = Wqh; off = i - 2 * n; }
        else if (i < 2 * n + 2 * wn) { src = Wk; dst = Wkh; off = i - 2 * n - wn; }
        else { src = Wv; dst = Wvh; off = i - 2 * n - 2 * wn; }
        float4 v = *((const float4*)src + off);
        h4 h = {(h_t)v.x, (h_t)v.y, (h_t)v.z, (h_t)v.w};
        *((h4*)dst + off) = h;
    } else {
        int tid = (int)(bid - 17920);                // 0..511
        const int K = 1024, N = 512;
        int nb = (tid & 15) * 32, kb = (tid >> 4) * 32;
        int x = threadIdx.x & 31, y = threadIdx.x >> 5;
#pragma unroll
        for (int j = 0; j < 4; j++)
            tile[y + j * 8][x] = Wo[(size_t)(kb + y + j * 8) * N + nb + x];
        __syncthreads();
#pragma unroll
        for (int j = 0; j < 4; j++)
            Wot[(size_t)(nb + y + j * 8) * K + kb + x] = (h_t)tile[x][y + j * 8];
    }
}

// ---------------- fused weight-fold GEMMs: Wkq (x log2e) and Wvot ----------------
__global__ __launch_bounds__(256) void k_wpre(const h_t* __restrict__ Wqh,
                                              const h_t* __restrict__ Wkh,
                                              const h_t* __restrict__ Wot,
                                              const h_t* __restrict__ Wvh,
                                              h_t* __restrict__ Wkq,
                                              h_t* __restrict__ Wvot) {
    __shared__ h_t As[128 * 64];
    __shared__ h_t Bs[128 * 64];
    int t = threadIdx.x, w = t >> 6, lane = t & 63;
    int q16 = lane >> 4, l16 = lane & 15;
    int id = blockIdx.x;
    const h_t* A;
    const h_t* Bt;
    h_t* C;
    float oscale;
    if (id < 16) { A = Wkh; Bt = Wqh; C = Wkq; oscale = 1.44269504f; }
    else { id -= 16; A = Wot; Bt = Wvh; C = Wvot; oscale = 1.0f; }
    size_t m0 = (size_t)(id >> 2) * 128, n0 = (size_t)(id & 3) * 128;
    const int K = 1024, N = 512;
    int wr = (w >> 1) * 64, wc = (w & 1) * 64;
    f4 acc[4][4] = {};

    for (int k0 = 0; k0 < K; k0 += 64) {
#pragma unroll
        for (int j = 0; j < 4; j++) {
            int q = w * 4 + j;
            int row = q * 8 + (lane >> 3);
            int ks = (((lane & 7) ^ (row & 7)) << 3);
            gl2lds16(A + (m0 + row) * K + k0 + ks, &As[q * 512]);
            gl2lds16(Bt + (n0 + row) * K + k0 + ks, &Bs[q * 512]);
        }
        __syncthreads();
#pragma unroll
        for (int ks = 0; ks < 2; ks++) {
            h8 av[4], bv[4];
#pragma unroll
            for (int i = 0; i < 4; i++) {
                int row = wr + i * 16 + l16;
                int ch = ks * 4 + q16;
                av[i] = *(const h8*)&As[row * 64 + ((ch ^ (row & 7)) << 3)];
            }
#pragma unroll
            for (int j = 0; j < 4; j++) {
                int row = wc + j * 16 + l16;
                int ch = ks * 4 + q16;
                bv[j] = *(const h8*)&Bs[row * 64 + ((ch ^ (row & 7)) << 3)];
            }
#pragma unroll
            for (int i = 0; i < 4; i++)
#pragma unroll
                for (int j = 0; j < 4; j++)
                    acc[i][j] = MFMA16(av[i], bv[j], acc[i][j]);
        }
        __syncthreads();
    }
#pragma unroll
    for (int i = 0; i < 4; i++) {
        size_t r0 = m0 + wr + i * 16 + q16 * 4;
#pragma unroll
        for (int j = 0; j < 4; j++) {
            size_t c = n0 + wc + j * 16 + l16;
#pragma unroll
            for (int r = 0; r < 4; r++)
                C[(r0 + r) * N + c] = (h_t)(acc[i][j][r] * oscale);
        }
    }
}

// ---------------- fused T / V'' projections (1024 blocks) -------------------------
__global__ __launch_bounds__(256) void k_proj2(const h_t* __restrict__ S2h,
                                               const h_t* __restrict__ S1h,
                                               const h_t* __restrict__ Wkq,
                                               const h_t* __restrict__ Wvot,
                                               const float* __restrict__ bo,
                                               h_t* __restrict__ T,
                                               h_t* __restrict__ Vt) {
    __shared__ h_t As[128 * 64];
    __shared__ h_t Bs[128 * 64];
    int t = threadIdx.x, w = t >> 6, lane = t & 63;
    int q16 = lane >> 4, l16 = lane & 15;
    int id = blockIdx.x;
    int mode = id >> 9;
    id &= 511;
    const h_t* A = mode ? S1h : S2h;
    const h_t* Bt = mode ? Wvot : Wkq;
    size_t m0 = (size_t)(id >> 2) * 128, n0 = (size_t)(id & 3) * 128;
    const int K = 512;
    int wr = (w >> 1) * 64, wc = (w & 1) * 64;
    f4 acc[4][4] = {};

    for (int k0 = 0; k0 < K; k0 += 64) {
#pragma unroll
        for (int j = 0; j < 4; j++) {
            int q = w * 4 + j;
            int row = q * 8 + (lane >> 3);
            int ks = (((lane & 7) ^ (row & 7)) << 3);
            gl2lds16(A + (m0 + row) * K + k0 + ks, &As[q * 512]);
            gl2lds16(Bt + (n0 + row) * K + k0 + ks, &Bs[q * 512]);
        }
        __syncthreads();
#pragma unroll
        for (int ks = 0; ks < 2; ks++) {
            h8 av[4], bv[4];
#pragma unroll
            for (int i = 0; i < 4; i++) {
                int row = wr + i * 16 + l16;
                int ch = ks * 4 + q16;
                av[i] = *(const h8*)&As[row * 64 + ((ch ^ (row & 7)) << 3)];
            }
#pragma unroll
            for (int j = 0; j < 4; j++) {
                int row = wc + j * 16 + l16;
                int ch = ks * 4 + q16;
                bv[j] = *(const h8*)&Bs[row * 64 + ((ch ^ (row & 7)) << 3)];
            }
#pragma unroll
            for (int i = 0; i < 4; i++)
#pragma unroll
                for (int j = 0; j < 4; j++)
                    acc[i][j] = MFMA16(av[i], bv[j], acc[i][j]);
        }
        __syncthreads();
    }
    if (mode == 0) {
#pragma unroll
        for (int i = 0; i < 4; i++) {
            size_t r0 = m0 + wr + i * 16 + q16 * 4;
#pragma unroll
            for (int j = 0; j < 4; j++) {
                size_t c = n0 + wc + j * 16 + l16;
#pragma unroll
                for (int r = 0; r < 4; r++)
                    T[(r0 + r) * 512 + c] = (h_t)acc[i][j][r];
            }
        }
    } else {
#pragma unroll
        for (int i = 0; i < 4; i++) {
            size_t gm = m0 + wr + i * 16 + q16 * 4;
            size_t b = gm >> 11;
            size_t n = gm & 2047;
#pragma unroll
            for (int j = 0; j < 4; j++) {
                size_t d = n0 + wc + j * 16 + l16;
                float bias = bo[d];
                h4 hv = {(h_t)(acc[i][j][0] + bias), (h_t)(acc[i][j][1] + bias),
                         (h_t)(acc[i][j][2] + bias), (h_t)(acc[i][j][3] + bias)};
                *(h4*)&Vt[(b * 512 + d) * 2048 + n] = hv;
            }
        }
    }
}

// ---------------- pass 1: S^T-tile GEMM (K=512) + local stats + P (exp2) ----------
// grid (qt 16, kt 16, b 8) = 2048 blocks, 256 thr. Swapped operands: keys =
// MFMA rows -> reduction mostly lane-local (cross-lane only over q16).
__global__ __launch_bounds__(256) void k_qk(const h_t* __restrict__ T,
                                            const h_t* __restrict__ S1h,
                                            h_t* __restrict__ P,
                                            float2* __restrict__ Mkt) {
    __shared__ h_t sm[18432];       // 36864B: GEMM As/Bs (32KB) | P-stage 128x136
    h_t* As = sm;                   // keys tile (S1h rows)
    h_t* Bs = sm + 8192;            // qrow tile (T rows)
    float* pmx = (float*)(sm + 17408);   // [2][128] wave-pair partial max
    float* psm = (float*)(sm + 17920);   // [2][128] wave-pair partial sum
    int t = threadIdx.x, w = t >> 6, lane = t & 63;
    int q16 = lane >> 4, l16 = lane & 15;
    int qt = blockIdx.x, kt = blockIdx.y, b = blockIdx.z;
    const h_t* A = S1h + ((size_t)b * 2048 + kt * 128) * 512;   // keys
    const h_t* Bt = T + ((size_t)b * 2048 + qt * 128) * 512;    // qrows
    int wr = (w >> 1) * 64, wc = (w & 1) * 64;  // wr = key-half, wc = qrow-half
    f4 acc[4][4] = {};

    for (int k0 = 0; k0 < 512; k0 += 64) {
#pragma unroll
        for (int j = 0; j < 4; j++) {
            int q = w * 4 + j;
            int row = q * 8 + (lane >> 3);
            int ks = (((lane & 7) ^ (row & 7)) << 3);
            gl2lds16(A + (size_t)row * 512 + k0 + ks, &As[q * 512]);
            gl2lds16(Bt + (size_t)row * 512 + k0 + ks, &Bs[q * 512]);
        }
        __syncthreads();
#pragma unroll
        for (int ks = 0; ks < 2; ks++) {
            h8 av[4], bv[4];
#pragma unroll
            for (int i = 0; i < 4; i++) {
                int row = wr + i * 16 + l16;
                int ch = ks * 4 + q16;
                av[i] = *(const h8*)&As[row * 64 + ((ch ^ (row & 7)) << 3)];
            }
#pragma unroll
            for (int j = 0; j < 4; j++) {
                int row = wc + j * 16 + l16;
                int ch = ks * 4 + q16;
                bv[j] = *(const h8*)&Bs[row * 64 + ((ch ^ (row & 7)) << 3)];
            }
#pragma unroll
            for (int i = 0; i < 4; i++)
#pragma unroll
                for (int j = 0; j < 4; j++)
                    acc[i][j] = MFMA16(av[i], bv[j], acc[i][j]);
        }
        __syncthreads();
    }
    // acc[i][j][r]: key = wr + i*16 + q16*4 + r, qrow = wc + j*16 + l16.
    float lm[4], ls[4], sc[4];
#pragma unroll
    for (int j = 0; j < 4; j++) {
        float m = acc[0][j][0];
#pragma unroll
        for (int i = 0; i < 4; i++)
#pragma unroll
            for (int r = 0; r < 4; r++) m = fmaxf(m, acc[i][j][r]);
        lm[j] = m;
    }
#pragma unroll
    for (int msk = 16; msk <= 32; msk <<= 1)
#pragma unroll
        for (int j = 0; j < 4; j++)
            lm[j] = fmaxf(lm[j], __shfl_xor(lm[j], msk, 64));
#pragma unroll
    for (int j = 0; j < 4; j++) {
        float s = 0.f;
#pragma unroll
        for (int i = 0; i < 4; i++)
#pragma unroll
            for (int r = 0; r < 4; r++) {
                float e = exp2f(acc[i][j][r] - lm[j]);
                acc[i][j][r] = e;       // keep e; rescale by sc at P-write
                s += e;
            }
        ls[j] = s;
    }
#pragma unroll
    for (int msk = 16; msk <= 32; msk <<= 1)
#pragma unroll
        for (int j = 0; j < 4; j++) ls[j] += __shfl_xor(ls[j], msk, 64);
    if (q16 == 0) {
#pragma unroll
        for (int j = 0; j < 4; j++) {
            pmx[(w >> 1) * 128 + wc + j * 16 + l16] = lm[j];
            psm[(w >> 1) * 128 + wc + j * 16 + l16] = ls[j];
        }
    }
    __syncthreads();   // partials visible (also: all GEMM reads of As/Bs done)
#pragma unroll
    for (int j = 0; j < 4; j++) {
        int row = wc + j * 16 + l16;
        float om = pmx[((w >> 1) ^ 1) * 128 + row];
        float os = psm[((w >> 1) ^ 1) * 128 + row];
        float M = fmaxf(lm[j], om);
        float s = exp2f(lm[j] - M);
        float L = ls[j] * s + os * exp2f(om - M);
        sc[j] = s;
        if ((w >> 1) == 0 && q16 == 0)
            Mkt[((size_t)b * 16 + kt) * 2048 + qt * 128 + row] = make_float2(M, L);
    }
    // ---- P-stage: sm[qrow][key], stride 136 (272B rows, 16B-aligned) ----
#pragma unroll
    for (int j = 0; j < 4; j++)
#pragma unroll
        for (int i = 0; i < 4; i++) {
            h4 hv = {(h_t)(acc[i][j][0] * sc[j]), (h_t)(acc[i][j][1] * sc[j]),
                     (h_t)(acc[i][j][2] * sc[j]), (h_t)(acc[i][j][3] * sc[j])};
            *(h4*)&sm[(wc + j * 16 + l16) * 136 + wr + i * 16 + q16 * 4] = hv;
        }
    __syncthreads();
    // ---- coalesced global store: P[qrow][key] row-major ----
    size_t Pbase = ((size_t)b * 2048 + qt * 128) * 2048 + (size_t)kt * 128;
#pragma unroll
    for (int p = 0; p < 8; p++) {
        int row = p * 16 + (t >> 4);
        int c8 = (t & 15) * 8;
        *(h8*)(P + Pbase + (size_t)row * 2048 + c8) = *(const h8*)&sm[row * 136 + c8];
    }
}

// ---------------- pass 2: O = sum_kt (P_kt * delta) @ V'', x 1/l_fin --------------
// grid (rt 16, dt 4, b 8) = 512 blocks, 256 thr, tile 128 rows x 128 d
// (k_gemm wave layout, 0.5 reads/MFMA). Stats prologue inlined: per block,
// Mkt[16][128 rows] -> m_fin, 1/l, per-kt deltas in LDS.
__global__ __launch_bounds__(256) void k_pv(const h_t* __restrict__ P,
                                            const h_t* __restrict__ Vt,
                                            const float2* __restrict__ Mkt,
                                            float* __restrict__ Out) {
    __shared__ h_t As[128 * 64];    // P-tile 16 KB (delta-scaled)
    __shared__ h_t Bs[128 * 64];    // V-tile 16 KB
    __shared__ h_t dks[16][128];    // per-kt row deltas, 4 KB
    __shared__ float linv[128];     // 0.5 KB
    int t = threadIdx.x, w = t >> 6, lane = t & 63;
    int q16 = lane >> 4, l16 = lane & 15;
    int rt = blockIdx.x, dt = blockIdx.y, b = blockIdx.z;
    int rg = w >> 1, dg = w & 1;
    // ---- stats prologue: rows rt*128..+127 ----
    if (t < 128) {
        float2 v[16];
        float m = -1e30f;
#pragma unroll
        for (int kt = 0; kt < 16; kt++) {
            v[kt] = Mkt[((size_t)b * 16 + kt) * 2048 + rt * 128 + t];
            m = fmaxf(m, v[kt].x);
        }
        float l = 0.f;
#pragma unroll
        for (int kt = 0; kt < 16; kt++) {
            float d = exp2f(v[kt].x - m);
            l += v[kt].y * d;
            dks[kt][t] = (h_t)d;
        }
        linv[t] = 1.f / l;
    }
    __syncthreads();

    const h_t* Pb = P + ((size_t)b * 2048 + rt * 128) * 2048;
    const h_t* Vb = Vt + ((size_t)b * 512 + dt * 128) * 2048;
    int srow = t >> 3, soct = t & 7;   // staging: row base / col octet
    f4 acc[4][4] = {};

    for (int k0 = 0; k0 < 2048; k0 += 64) {
        int kt = k0 >> 7;
        // A-stage: P rows (4 per thread), delta folded in, swizzled ds_write
#pragma unroll
        for (int p = 0; p < 4; p++) {
            int r_ = p * 32 + srow;
            h_t dh = dks[kt][r_];
            h8 dv = {dh, dh, dh, dh, dh, dh, dh, dh};
            h8 v = *(const h8*)(Pb + (size_t)r_ * 2048 + k0 + soct * 8);
            v = v * dv;
            *(h8*)&As[r_ * 64 + ((soct ^ (r_ & 7)) << 3)] = v;
        }
        // B-stage: V via gl2lds (k_gemm pattern)
#pragma unroll
        for (int j = 0; j < 4; j++) {
            int q = w * 4 + j;
            int row = q * 8 + (lane >> 3);
            int ks = (((lane & 7) ^ (row & 7)) << 3);
            gl2lds16(Vb + (size_t)row * 2048 + k0 + ks, &Bs[q * 512]);
        }
        __syncthreads();
#pragma unroll
        for (int ks = 0; ks < 2; ks++) {
            int ch = ks * 4 + q16;
            h8 av[4], bv[4];
#pragma unroll
            for (int i = 0; i < 4; i++) {
                int row = rg * 64 + i * 16 + l16;
                av[i] = *(const h8*)&As[row * 64 + ((ch ^ (row & 7)) << 3)];
            }
#pragma unroll
            for (int j = 0; j < 4; j++) {
                int dr = dg * 64 + j * 16 + l16;
                bv[j] = *(const h8*)&Bs[dr * 64 + ((ch ^ (dr & 7)) << 3)];
            }
#pragma unroll
            for (int i = 0; i < 4; i++)
#pragma unroll
                for (int j = 0; j < 4; j++)
                    acc[i][j] = MFMA16(av[i], bv[j], acc[i][j]);
        }
        __syncthreads();
    }
#pragma unroll
    for (int i = 0; i < 4; i++)
#pragma unroll
        for (int rr = 0; rr < 4; rr++) {
            int row = rg * 64 + i * 16 + q16 * 4 + rr;
            float lv = linv[row];
#pragma unroll
            for (int j = 0; j < 4; j++) {
                int d = dt * 128 + dg * 64 + j * 16 + l16;
                Out[((size_t)b * 2048 + rt * 128 + row) * 512 + d] =
                    acc[i][j][rr] * lv;
            }
        }
}

// ---------------- host ----------------
extern "C" void kernel_launch(void* const* d_in, const int* in_sizes, int n_in,
                              void* d_out, int out_size, void* d_ws, size_t ws_size,
                              hipStream_t stream) {
    const float* S1 = (const float*)d_in[0];
    const float* S2 = (const float*)d_in[1];
    const float* Wq = (const float*)d_in[2];
    const float* Wk = (const float*)d_in[3];
    const float* Wv = (const float*)d_in[4];
    const float* Wo = (const float*)d_in[5];
    const float* bo = (const float*)d_in[6];
    float* Out = (float*)d_out;

    char* ws = (char*)d_ws;
    // persistent through attention:
    h_t* S1h  = (h_t*)(ws);                  // 16 MB (live through k_qk)
    h_t* T    = (h_t*)(ws + 16777216);       // 16 MB (live through k_qk)
    h_t* Vt   = (h_t*)(ws + 33554432);       // 16 MB (live through k_pv)
    h_t* P    = (h_t*)(ws + 50331648);       // 64 MB [8][2048][2048]
    float2* Mkt = (float2*)(ws + 117440512); // 2 MB [8][16][2048]
    // aliases inside P (all dead before k_qk writes P):
    h_t* S2h  = (h_t*)(ws + 50331648);       // 16 MB (dead after k_proj2)
    h_t* Wqh  = (h_t*)(ws + 67108864);       // 1 MB
    h_t* Wkh  = (h_t*)(ws + 68157440);       // 1 MB
    h_t* Wvh  = (h_t*)(ws + 69206016);       // 1 MB
    h_t* Wot  = (h_t*)(ws + 70254592);       // 1 MB
    h_t* Wkq  = (h_t*)(ws + 71303168);       // 0.5 MB
    h_t* Wvot = (h_t*)(ws + 71827456);       // 0.5 MB

    k_prep<<<18432, 256, 0, stream>>>(S1, S2, Wq, Wk, Wv, Wo,
                                      S1h, S2h, Wqh, Wkh, Wvh, Wot);
    k_wpre<<<32, 256, 0, stream>>>(Wqh, Wkh, Wot, Wvh, Wkq, Wvot);
    k_proj2<<<1024, 256, 0, stream>>>(S2h, S1h, Wkq, Wvot, bo, T, Vt);
    k_qk<<<dim3(16, 16, 8), 256, 0, stream>>>(T, S1h, P, Mkt);
    k_pv<<<dim3(16, 4, 8), 256, 0, stream>>>(P, Vt, Mkt, Out);
}

// Round 10
// 277.186 us; speedup vs baseline: 1.8362x; 1.0115x over previous
//
#include <hip/hip_runtime.h>

// CrossAttention: out = softmax((S2 Wq)(S1 Wk)^T) (S1 Wv) Wo + bo
// R16 = R15 (Wkq fold, exp2 domain, swapped-operand k_qk, single-P two-pass,
// 5 dispatches) + T3/T4-minimum pipeline (R9-proven pattern) in the three hot
// GEMMs: double-buffered staging, counted s_waitcnt vmcnt(8) (never 0 in the
// main loop), raw s_barrier. k_pv's P-side is software-pipelined in REGISTERS
// with statically named prA/prB (no runtime-indexed reg arrays -> no scratch).
// Epilogues and math byte-identical to R15 (absmax guard 0.01171875).

typedef _Float16 h_t;
typedef _Float16 h8 __attribute__((ext_vector_type(8)));
typedef _Float16 h4 __attribute__((ext_vector_type(4)));
typedef float f4 __attribute__((ext_vector_type(4)));

#define MFMA16(a, b, c) __builtin_amdgcn_mfma_f32_16x16x32_f16(a, b, c, 0, 0, 0)

typedef const __attribute__((address_space(1))) void* gas_t;
typedef __attribute__((address_space(3))) void* las_t;

__device__ __forceinline__ void gl2lds16(const void* g, void* l) {
    __builtin_amdgcn_global_load_lds((gas_t)g, (las_t)l, 16, 0, 0);
}

// ---------------- merged prep: cast S1,S2,Wq,Wk,Wv + transpose Wo ----------------
__global__ __launch_bounds__(256) void k_prep(const float* __restrict__ S1,
                                              const float* __restrict__ S2,
                                              const float* __restrict__ Wq,
                                              const float* __restrict__ Wk,
                                              const float* __restrict__ Wv,
                                              const float* __restrict__ Wo,
                                              h_t* __restrict__ S1h,
                                              h_t* __restrict__ S2h,
                                              h_t* __restrict__ Wqh,
                                              h_t* __restrict__ Wkh,
                                              h_t* __restrict__ Wvh,
                                              h_t* __restrict__ Wot) {
    __shared__ float tile[32][33];
    long bid = blockIdx.x;
    if (bid < 17920) {
        long i = bid * 256 + threadIdx.x;            // f4 index
        const long n = 2097152;                       // S1/S2 f4 count
        const long wn = 131072;                       // weight f4 count
        const float* src;
        h_t* dst;
        long off;
        if (i < n) { src = S1; dst = S1h; off = i; }
        else if (i < 2 * n) { src = S2; dst = S2h; off = i - n; }
        else if (i < 2 * n + wn) { src = Wq; dst = Wqh; off = i - 2 * n; }
        else if (i < 2 * n + 2 * wn) { src = Wk; dst = Wkh; off = i - 2 * n - wn; }
        else { src = Wv; dst = Wvh; off = i - 2 * n - 2 * wn; }
        float4 v = *((const float4*)src + off);
        h4 h = {(h_t)v.x, (h_t)v.y, (h_t)v.z, (h_t)v.w};
        *((h4*)dst + off) = h;
    } else {
        int tid = (int)(bid - 17920);                // 0..511
        const int K = 1024, N = 512;
        int nb = (tid & 15) * 32, kb = (tid >> 4) * 32;
        int x = threadIdx.x & 31, y = threadIdx.x >> 5;
#pragma unroll
        for (int j = 0; j < 4; j++)
            tile[y + j * 8][x] = Wo[(size_t)(kb + y + j * 8) * N + nb + x];
        __syncthreads();
#pragma unroll
        for (int j = 0; j < 4; j++)
            Wot[(size_t)(nb + y + j * 8) * K + kb + x] = (h_t)tile[x][y + j * 8];
    }
}

// ---------------- fused weight-fold GEMMs: Wkq (x log2e) and Wvot ----------------
__global__ __launch_bounds__(256) void k_wpre(const h_t* __restrict__ Wqh,
                                              const h_t* __restrict__ Wkh,
                                              const h_t* __restrict__ Wot,
                                              const h_t* __restrict__ Wvh,
                                              h_t* __restrict__ Wkq,
                                              h_t* __restrict__ Wvot) {
    __shared__ h_t As[128 * 64];
    __shared__ h_t Bs[128 * 64];
    int t = threadIdx.x, w = t >> 6, lane = t & 63;
    int q16 = lane >> 4, l16 = lane & 15;
    int id = blockIdx.x;
    const h_t* A;
    const h_t* Bt;
    h_t* C;
    float oscale;
    if (id < 16) { A = Wkh; Bt = Wqh; C = Wkq; oscale = 1.44269504f; }
    else { id -= 16; A = Wot; Bt = Wvh; C = Wvot; oscale = 1.0f; }
    size_t m0 = (size_t)(id >> 2) * 128, n0 = (size_t)(id & 3) * 128;
    const int K = 1024, N = 512;
    int wr = (w >> 1) * 64, wc = (w & 1) * 64;
    f4 acc[4][4] = {};

    for (int k0 = 0; k0 < K; k0 += 64) {
#pragma unroll
        for (int j = 0; j < 4; j++) {
            int q = w * 4 + j;
            int row = q * 8 + (lane >> 3);
            int ks = (((lane & 7) ^ (row & 7)) << 3);
            gl2lds16(A + (m0 + row) * K + k0 + ks, &As[q * 512]);
            gl2lds16(Bt + (n0 + row) * K + k0 + ks, &Bs[q * 512]);
        }
        __syncthreads();
#pragma unroll
        for (int ks = 0; ks < 2; ks++) {
            h8 av[4], bv[4];
#pragma unroll
            for (int i = 0; i < 4; i++) {
                int row = wr + i * 16 + l16;
                int ch = ks * 4 + q16;
                av[i] = *(const h8*)&As[row * 64 + ((ch ^ (row & 7)) << 3)];
            }
#pragma unroll
            for (int j = 0; j < 4; j++) {
                int row = wc + j * 16 + l16;
                int ch = ks * 4 + q16;
                bv[j] = *(const h8*)&Bs[row * 64 + ((ch ^ (row & 7)) << 3)];
            }
#pragma unroll
            for (int i = 0; i < 4; i++)
#pragma unroll
                for (int j = 0; j < 4; j++)
                    acc[i][j] = MFMA16(av[i], bv[j], acc[i][j]);
        }
        __syncthreads();
    }
#pragma unroll
    for (int i = 0; i < 4; i++) {
        size_t r0 = m0 + wr + i * 16 + q16 * 4;
#pragma unroll
        for (int j = 0; j < 4; j++) {
            size_t c = n0 + wc + j * 16 + l16;
#pragma unroll
            for (int r = 0; r < 4; r++)
                C[(r0 + r) * N + c] = (h_t)(acc[i][j][r] * oscale);
        }
    }
}

// ---------------- fused T / V'' projections (1024 blocks), PIPELINED --------------
__global__ __launch_bounds__(256) void k_proj2(const h_t* __restrict__ S2h,
                                               const h_t* __restrict__ S1h,
                                               const h_t* __restrict__ Wkq,
                                               const h_t* __restrict__ Wvot,
                                               const float* __restrict__ bo,
                                               h_t* __restrict__ T,
                                               h_t* __restrict__ Vt) {
    __shared__ h_t smem[2][16384];  // 64 KB: buf[i] = As(8192 h) + Bs(8192 h)
    int t = threadIdx.x, w = t >> 6, lane = t & 63;
    int q16 = lane >> 4, l16 = lane & 15;
    int id = blockIdx.x;
    int mode = id >> 9;
    id &= 511;
    const h_t* A = mode ? S1h : S2h;
    const h_t* Bt = mode ? Wvot : Wkq;
    size_t m0 = (size_t)(id >> 2) * 128, n0 = (size_t)(id & 3) * 128;
    int wr = (w >> 1) * 64, wc = (w & 1) * 64;
    f4 acc[4][4] = {};

    auto STAGE = [&](int k0_, int bsel) {
#pragma unroll
        for (int j = 0; j < 4; j++) {
            int q = w * 4 + j;
            int row = q * 8 + (lane >> 3);
            int ks = (((lane & 7) ^ (row & 7)) << 3);
            gl2lds16(A + (m0 + row) * 512 + k0_ + ks, &smem[bsel][q * 512]);
            gl2lds16(Bt + (n0 + row) * 512 + k0_ + ks, &smem[bsel][8192 + q * 512]);
        }
    };

    STAGE(0, 0);
    int cur = 0;
#pragma unroll 1
    for (int it = 0; it < 8; it++) {
        if (it < 7) {
            STAGE((it + 1) * 64, cur ^ 1);
            asm volatile("s_waitcnt vmcnt(8)" ::: "memory");
        } else {
            asm volatile("s_waitcnt vmcnt(0)" ::: "memory");
        }
        __builtin_amdgcn_s_barrier();
        asm volatile("" ::: "memory");
        const h_t* As = &smem[cur][0];
        const h_t* Bs = &smem[cur][8192];
#pragma unroll
        for (int ks = 0; ks < 2; ks++) {
            h8 av[4], bv[4];
#pragma unroll
            for (int i = 0; i < 4; i++) {
                int row = wr + i * 16 + l16;
                int ch = ks * 4 + q16;
                av[i] = *(const h8*)&As[row * 64 + ((ch ^ (row & 7)) << 3)];
            }
#pragma unroll
            for (int j = 0; j < 4; j++) {
                int row = wc + j * 16 + l16;
                int ch = ks * 4 + q16;
                bv[j] = *(const h8*)&Bs[row * 64 + ((ch ^ (row & 7)) << 3)];
            }
#pragma unroll
            for (int i = 0; i < 4; i++)
#pragma unroll
                for (int j = 0; j < 4; j++)
                    acc[i][j] = MFMA16(av[i], bv[j], acc[i][j]);
        }
        asm volatile("" ::: "memory");
        __builtin_amdgcn_s_barrier();
        cur ^= 1;
    }
    if (mode == 0) {
#pragma unroll
        for (int i = 0; i < 4; i++) {
            size_t r0 = m0 + wr + i * 16 + q16 * 4;
#pragma unroll
            for (int j = 0; j < 4; j++) {
                size_t c = n0 + wc + j * 16 + l16;
#pragma unroll
                for (int r = 0; r < 4; r++)
                    T[(r0 + r) * 512 + c] = (h_t)acc[i][j][r];
            }
        }
    } else {
#pragma unroll
        for (int i = 0; i < 4; i++) {
            size_t gm = m0 + wr + i * 16 + q16 * 4;
            size_t b = gm >> 11;
            size_t n = gm & 2047;
#pragma unroll
            for (int j = 0; j < 4; j++) {
                size_t d = n0 + wc + j * 16 + l16;
                float bias = bo[d];
                h4 hv = {(h_t)(acc[i][j][0] + bias), (h_t)(acc[i][j][1] + bias),
                         (h_t)(acc[i][j][2] + bias), (h_t)(acc[i][j][3] + bias)};
                *(h4*)&Vt[(b * 512 + d) * 2048 + n] = hv;
            }
        }
    }
}

// ---------------- pass 1: S^T-tile GEMM (K=512, PIPELINED) + stats + P ------------
// grid (qt 16, kt 16, b 8) = 2048 blocks, 256 thr. Swapped operands: keys =
// MFMA rows -> reduction mostly lane-local (cross-lane only over q16).
__global__ __launch_bounds__(256) void k_qk(const h_t* __restrict__ T,
                                            const h_t* __restrict__ S1h,
                                            h_t* __restrict__ P,
                                            float2* __restrict__ Mkt) {
    __shared__ h_t smem[2][16384];  // 64 KB: buf[i] = keys(8192 h) + qrows(8192 h)
    __shared__ float pmx[2][128], psm[2][128];
    h_t* Ps = &smem[0][0];          // P-stage 128x136 h (34816 B), aliases bufs
    int t = threadIdx.x, w = t >> 6, lane = t & 63;
    int q16 = lane >> 4, l16 = lane & 15;
    int qt = blockIdx.x, kt = blockIdx.y, b = blockIdx.z;
    const h_t* A = S1h + ((size_t)b * 2048 + kt * 128) * 512;   // keys
    const h_t* Bt = T + ((size_t)b * 2048 + qt * 128) * 512;    // qrows
    int wr = (w >> 1) * 64, wc = (w & 1) * 64;  // wr = key-half, wc = qrow-half
    f4 acc[4][4] = {};

    auto STAGE = [&](int k0_, int bsel) {
#pragma unroll
        for (int j = 0; j < 4; j++) {
            int q = w * 4 + j;
            int row = q * 8 + (lane >> 3);
            int ks = (((lane & 7) ^ (row & 7)) << 3);
            gl2lds16(A + (size_t)row * 512 + k0_ + ks, &smem[bsel][q * 512]);
            gl2lds16(Bt + (size_t)row * 512 + k0_ + ks, &smem[bsel][8192 + q * 512]);
        }
    };

    STAGE(0, 0);
    int cur = 0;
#pragma unroll 1
    for (int it = 0; it < 8; it++) {
        if (it < 7) {
            STAGE((it + 1) * 64, cur ^ 1);
            asm volatile("s_waitcnt vmcnt(8)" ::: "memory");
        } else {
            asm volatile("s_waitcnt vmcnt(0)" ::: "memory");
        }
        __builtin_amdgcn_s_barrier();
        asm volatile("" ::: "memory");
        const h_t* As = &smem[cur][0];
        const h_t* Bs = &smem[cur][8192];
#pragma unroll
        for (int ks = 0; ks < 2; ks++) {
            h8 av[4], bv[4];
#pragma unroll
            for (int i = 0; i < 4; i++) {
                int row = wr + i * 16 + l16;
                int ch = ks * 4 + q16;
                av[i] = *(const h8*)&As[row * 64 + ((ch ^ (row & 7)) << 3)];
            }
#pragma unroll
            for (int j = 0; j < 4; j++) {
                int row = wc + j * 16 + l16;
                int ch = ks * 4 + q16;
                bv[j] = *(const h8*)&Bs[row * 64 + ((ch ^ (row & 7)) << 3)];
            }
#pragma unroll
            for (int i = 0; i < 4; i++)
#pragma unroll
                for (int j = 0; j < 4; j++)
                    acc[i][j] = MFMA16(av[i], bv[j], acc[i][j]);
        }
        asm volatile("" ::: "memory");
        __builtin_amdgcn_s_barrier();
        cur ^= 1;
    }
    // acc[i][j][r]: key = wr + i*16 + q16*4 + r, qrow = wc + j*16 + l16.
    float lm[4], ls[4], sc[4];
#pragma unroll
    for (int j = 0; j < 4; j++) {
        float m = acc[0][j][0];
#pragma unroll
        for (int i = 0; i < 4; i++)
#pragma unroll
            for (int r = 0; r < 4; r++) m = fmaxf(m, acc[i][j][r]);
        lm[j] = m;
    }
#pragma unroll
    for (int msk = 16; msk <= 32; msk <<= 1)
#pragma unroll
        for (int j = 0; j < 4; j++)
            lm[j] = fmaxf(lm[j], __shfl_xor(lm[j], msk, 64));
#pragma unroll
    for (int j = 0; j < 4; j++) {
        float s = 0.f;
#pragma unroll
        for (int i = 0; i < 4; i++)
#pragma unroll
            for (int r = 0; r < 4; r++) {
                float e = exp2f(acc[i][j][r] - lm[j]);
                acc[i][j][r] = e;       // keep e; rescale by sc at P-write
                s += e;
            }
        ls[j] = s;
    }
#pragma unroll
    for (int msk = 16; msk <= 32; msk <<= 1)
#pragma unroll
        for (int j = 0; j < 4; j++) ls[j] += __shfl_xor(ls[j], msk, 64);
    if (q16 == 0) {
#pragma unroll
        for (int j = 0; j < 4; j++) {
            pmx[w >> 1][wc + j * 16 + l16] = lm[j];
            psm[w >> 1][wc + j * 16 + l16] = ls[j];
        }
    }
    __syncthreads();   // partials visible (all GEMM reads of smem also done)
#pragma unroll
    for (int j = 0; j < 4; j++) {
        int row = wc + j * 16 + l16;
        float om = pmx[(w >> 1) ^ 1][row];
        float os = psm[(w >> 1) ^ 1][row];
        float M = fmaxf(lm[j], om);
        float s = exp2f(lm[j] - M);
        float L = ls[j] * s + os * exp2f(om - M);
        sc[j] = s;
        if ((w >> 1) == 0 && q16 == 0)
            Mkt[((size_t)b * 16 + kt) * 2048 + qt * 128 + row] = make_float2(M, L);
    }
    // ---- P-stage: Ps[qrow][key], stride 136 (272B rows, 16B-aligned) ----
#pragma unroll
    for (int j = 0; j < 4; j++)
#pragma unroll
        for (int i = 0; i < 4; i++) {
            h4 hv = {(h_t)(acc[i][j][0] * sc[j]), (h_t)(acc[i][j][1] * sc[j]),
                     (h_t)(acc[i][j][2] * sc[j]), (h_t)(acc[i][j][3] * sc[j])};
            *(h4*)&Ps[(wc + j * 16 + l16) * 136 + wr + i * 16 + q16 * 4] = hv;
        }
    __syncthreads();
    // ---- coalesced global store: P[qrow][key] row-major ----
    size_t Pbase = ((size_t)b * 2048 + qt * 128) * 2048 + (size_t)kt * 128;
#pragma unroll
    for (int p = 0; p < 8; p++) {
        int row = p * 16 + (t >> 4);
        int c8 = (t & 15) * 8;
        *(h8*)(P + Pbase + (size_t)row * 2048 + c8) = *(const h8*)&Ps[row * 136 + c8];
    }
}

// ---------------- pass 2: O = sum_kt (P_kt * delta) @ V'', x 1/l_fin --------------
// grid (rt 16, dt 4, b 8) = 512 blocks, 256 thr, tile 128x128. PIPELINED:
// V double-buffered via gl2lds; P software-pipelined in registers (prA/prB
// statically named). Per phase: 8 newer ops in flight -> vmcnt(8) retires
// exactly the current phase's P-regs + V-tile. Stats prologue inlined.
__global__ __launch_bounds__(256) void k_pv(const h_t* __restrict__ P,
                                            const h_t* __restrict__ Vt,
                                            const float2* __restrict__ Mkt,
                                            float* __restrict__ Out) {
    __shared__ h_t As[128 * 64];    // P-tile 16 KB (delta-scaled), single
    __shared__ h_t Bs[2][128 * 64]; // V-tiles 2 x 16 KB
    __shared__ h_t dks[16][128];    // per-kt row deltas, 4 KB
    __shared__ float linv[128];     // 0.5 KB
    int t = threadIdx.x, w = t >> 6, lane = t & 63;
    int q16 = lane >> 4, l16 = lane & 15;
    int rt = blockIdx.x, dt = blockIdx.y, b = blockIdx.z;
    int rg = w >> 1, dg = w & 1;
    // ---- stats prologue: rows rt*128..+127 ----
    if (t < 128) {
        float2 v[16];
        float m = -1e30f;
#pragma unroll
        for (int kt = 0; kt < 16; kt++) {
            v[kt] = Mkt[((size_t)b * 16 + kt) * 2048 + rt * 128 + t];
            m = fmaxf(m, v[kt].x);
        }
        float l = 0.f;
#pragma unroll
        for (int kt = 0; kt < 16; kt++) {
            float d = exp2f(v[kt].x - m);
            l += v[kt].y * d;
            dks[kt][t] = (h_t)d;
        }
        linv[t] = 1.f / l;
    }
    __syncthreads();

    const h_t* Pb = P + ((size_t)b * 2048 + rt * 128) * 2048;
    const h_t* Vb = Vt + ((size_t)b * 512 + dt * 128) * 2048;
    int srow = t >> 3, soct = t & 7;   // staging: row base / col octet
    f4 acc[4][4] = {};
    h8 prA[4], prB[4];

    auto VSTAGE = [&](int k0_, int bsel) {
#pragma unroll
        for (int j = 0; j < 4; j++) {
            int q = w * 4 + j;
            int row = q * 8 + (lane >> 3);
            int ks = (((lane & 7) ^ (row & 7)) << 3);
            gl2lds16(Vb + (size_t)row * 2048 + k0_ + ks, &Bs[bsel][q * 512]);
        }
    };
    // A-stage from named regs: delta-multiply, swizzled ds_write into As
    auto ASTORE = [&](h8* pr, int kt_) {
#pragma unroll
        for (int p = 0; p < 4; p++) {
            int r_ = p * 32 + srow;
            h_t dh = dks[kt_][r_];
            h8 dv = {dh, dh, dh, dh, dh, dh, dh, dh};
            h8 v = pr[p] * dv;
            *(h8*)&As[r_ * 64 + ((soct ^ (r_ & 7)) << 3)] = v;
        }
    };
    auto MM = [&](const h_t* Bsc) {
#pragma unroll
        for (int ks = 0; ks < 2; ks++) {
            int ch = ks * 4 + q16;
            h8 av[4], bv[4];
#pragma unroll
            for (int i = 0; i < 4; i++) {
                int row = rg * 64 + i * 16 + l16;
                av[i] = *(const h8*)&As[row * 64 + ((ch ^ (row & 7)) << 3)];
            }
#pragma unroll
            for (int j = 0; j < 4; j++) {
                int dr = dg * 64 + j * 16 + l16;
                bv[j] = *(const h8*)&Bsc[dr * 64 + ((ch ^ (dr & 7)) << 3)];
            }
#pragma unroll
            for (int i = 0; i < 4; i++)
#pragma unroll
                for (int j = 0; j < 4; j++)
                    acc[i][j] = MFMA16(av[i], bv[j], acc[i][j]);
        }
    };

    // prologue: phase 0 P-regs + V-tile
#pragma unroll
    for (int p = 0; p < 4; p++)
        prA[p] = *(const h8*)(Pb + (size_t)(p * 32 + srow) * 2048 + soct * 8);
    VSTAGE(0, 0);

#pragma unroll 1
    for (int it2 = 0; it2 < 16; it2++) {
        int k0 = it2 * 128;
        // ---- even phase: buf0 / prA; prefetch k0+64 -> prB, buf1 ----
#pragma unroll
        for (int p = 0; p < 4; p++)
            prB[p] = *(const h8*)(Pb + (size_t)(p * 32 + srow) * 2048 + k0 + 64 + soct * 8);
        VSTAGE(k0 + 64, 1);
        asm volatile("s_waitcnt vmcnt(8)" ::: "memory");  // prA + V(buf0) ready
        ASTORE(prA, k0 >> 7);
        asm volatile("s_waitcnt lgkmcnt(0)" ::: "memory");
        __builtin_amdgcn_s_barrier();
        asm volatile("" ::: "memory");
        MM(&Bs[0][0]);
        asm volatile("" ::: "memory");
        __builtin_amdgcn_s_barrier();
        // ---- odd phase: buf1 / prB; prefetch k0+128 -> prA, buf0 ----
        if (it2 < 15) {
#pragma unroll
            for (int p = 0; p < 4; p++)
                prA[p] = *(const h8*)(Pb + (size_t)(p * 32 + srow) * 2048 + k0 + 128 + soct * 8);
            VSTAGE(k0 + 128, 0);
            asm volatile("s_waitcnt vmcnt(8)" ::: "memory");  // prB + V(buf1)
        } else {
            asm volatile("s_waitcnt vmcnt(0)" ::: "memory");
        }
        ASTORE(prB, (k0 + 64) >> 7);
        asm volatile("s_waitcnt lgkmcnt(0)" ::: "memory");
        __builtin_amdgcn_s_barrier();
        asm volatile("" ::: "memory");
        MM(&Bs[1][0]);
        asm volatile("" ::: "memory");
        __builtin_amdgcn_s_barrier();
    }
#pragma unroll
    for (int i = 0; i < 4; i++)
#pragma unroll
        for (int rr = 0; rr < 4; rr++) {
            int row = rg * 64 + i * 16 + q16 * 4 + rr;
            float lv = linv[row];
#pragma unroll
            for (int j = 0; j < 4; j++) {
                int d = dt * 128 + dg * 64 + j * 16 + l16;
                Out[((size_t)b * 2048 + rt * 128 + row) * 512 + d] =
                    acc[i][rr >= 0 ? j : j][rr] * lv;
            }
        }
}

// ---------------- host ----------------
extern "C" void kernel_launch(void* const* d_in, const int* in_sizes, int n_in,
                              void* d_out, int out_size, void* d_ws, size_t ws_size,
                              hipStream_t stream) {
    const float* S1 = (const float*)d_in[0];
    const float* S2 = (const float*)d_in[1];
    const float* Wq = (const float*)d_in[2];
    const float* Wk = (const float*)d_in[3];
    const float* Wv = (const float*)d_in[4];
    const float* Wo = (const float*)d_in[5];
    const float* bo = (const float*)d_in[6];
    float* Out = (float*)d_out;

    char* ws = (char*)d_ws;
    // persistent through attention:
    h_t* S1h  = (h_t*)(ws);                  // 16 MB (live through k_qk)
    h_t* T    = (h_t*)(ws + 16777216);       // 16 MB (live through k_qk)
    h_t* Vt   = (h_t*)(ws + 33554432);       // 16 MB (live through k_pv)
    h_t* P    = (h_t*)(ws + 50331648);       // 64 MB [8][2048][2048]
    float2* Mkt = (float2*)(ws + 117440512); // 2 MB [8][16][2048]
    // aliases inside P (all dead before k_qk writes P):
    h_t* S2h  = (h_t*)(ws + 50331648);       // 16 MB (dead after k_proj2)
    h_t* Wqh  = (h_t*)(ws + 67108864);       // 1 MB
    h_t* Wkh  = (h_t*)(ws + 68157440);       // 1 MB
    h_t* Wvh  = (h_t*)(ws + 69206016);       // 1 MB
    h_t* Wot  = (h_t*)(ws + 70254592);       // 1 MB
    h_t* Wkq  = (h_t*)(ws + 71303168);       // 0.5 MB
    h_t* Wvot = (h_t*)(ws + 71827456);       // 0.5 MB

    k_prep<<<18432, 256, 0, stream>>>(S1, S2, Wq, Wk, Wv, Wo,
                                      S1h, S2h, Wqh, Wkh, Wvh, Wot);
    k_wpre<<<32, 256, 0, stream>>>(Wqh, Wkh, Wot, Wvh, Wkq, Wvot);
    k_proj2<<<1024, 256, 0, stream>>>(S2h, S1h, Wkq, Wvot, bo, T, Vt);
    k_qk<<<dim3(16, 16, 8), 256, 0, stream>>>(T, S1h, P, Mkt);
    k_pv<<<dim3(16, 4, 8), 256, 0, stream>>>(P, Vt, Mkt, Out);
}

// Round 11
// 276.131 us; speedup vs baseline: 1.8432x; 1.0038x over previous
//
#include <hip/hip_runtime.h>

// CrossAttention: out = softmax((S2 Wq)(S1 Wk)^T) (S1 Wv) Wo + bo
// R17 = R16 (Wkq fold, exp2 domain, swapped-operand two-pass attention,
// counted-vmcnt pipelines) with k_qk scaled to a 256x256 tile / 512 threads
// (8 waves = 2 key-groups x 4 qrow-groups), BK=64 double-buffer:
//  - 0.375 LDS-reads/MFMA (was 0.5), half the barriers per MFMA,
//  - halved operand strip redundancy (FETCH ~74 -> ~56 MB),
//  - same vmcnt(8) staging ledger as the proven R16 loop,
//  - P-stage reuses dead GEMM buffers in two 128-row rounds (stride 264 h),
//  - Mkt now 8 tiles of 256 keys; k_pv prologue updated (dks[8], kt=k0>>8).
// Math identical (absmax guard 0.01171875). Registers: 128 AGPR acc + ~100
// VGPR < 256 cap at launch_bounds(512,2); spill guard = k_qk WRITE_SIZE.

typedef _Float16 h_t;
typedef _Float16 h8 __attribute__((ext_vector_type(8)));
typedef _Float16 h4 __attribute__((ext_vector_type(4)));
typedef float f4 __attribute__((ext_vector_type(4)));

#define MFMA16(a, b, c) __builtin_amdgcn_mfma_f32_16x16x32_f16(a, b, c, 0, 0, 0)

typedef const __attribute__((address_space(1))) void* gas_t;
typedef __attribute__((address_space(3))) void* las_t;

__device__ __forceinline__ void gl2lds16(const void* g, void* l) {
    __builtin_amdgcn_global_load_lds((gas_t)g, (las_t)l, 16, 0, 0);
}

// ---------------- merged prep: cast S1,S2,Wq,Wk,Wv + transpose Wo ----------------
__global__ __launch_bounds__(256) void k_prep(const float* __restrict__ S1,
                                              const float* __restrict__ S2,
                                              const float* __restrict__ Wq,
                                              const float* __restrict__ Wk,
                                              const float* __restrict__ Wv,
                                              const float* __restrict__ Wo,
                                              h_t* __restrict__ S1h,
                                              h_t* __restrict__ S2h,
                                              h_t* __restrict__ Wqh,
                                              h_t* __restrict__ Wkh,
                                              h_t* __restrict__ Wvh,
                                              h_t* __restrict__ Wot) {
    __shared__ float tile[32][33];
    long bid = blockIdx.x;
    if (bid < 17920) {
        long i = bid * 256 + threadIdx.x;            // f4 index
        const long n = 2097152;                       // S1/S2 f4 count
        const long wn = 131072;                       // weight f4 count
        const float* src;
        h_t* dst;
        long off;
        if (i < n) { src = S1; dst = S1h; off = i; }
        else if (i < 2 * n) { src = S2; dst = S2h; off = i - n; }
        else if (i < 2 * n + wn) { src = Wq; dst = Wqh; off = i - 2 * n; }
        else if (i < 2 * n + 2 * wn) { src = Wk; dst = Wkh; off = i - 2 * n - wn; }
        else { src = Wv; dst = Wvh; off = i - 2 * n - 2 * wn; }
        float4 v = *((const float4*)src + off);
        h4 h = {(h_t)v.x, (h_t)v.y, (h_t)v.z, (h_t)v.w};
        *((h4*)dst + off) = h;
    } else {
        int tid = (int)(bid - 17920);                // 0..511
        const int K = 1024, N = 512;
        int nb = (tid & 15) * 32, kb = (tid >> 4) * 32;
        int x = threadIdx.x & 31, y = threadIdx.x >> 5;
#pragma unroll
        for (int j = 0; j < 4; j++)
            tile[y + j * 8][x] = Wo[(size_t)(kb + y + j * 8) * N + nb + x];
        __syncthreads();
#pragma unroll
        for (int j = 0; j < 4; j++)
            Wot[(size_t)(nb + y + j * 8) * K + kb + x] = (h_t)tile[x][y + j * 8];
    }
}

// ---------------- fused weight-fold GEMMs: Wkq (x log2e) and Wvot ----------------
__global__ __launch_bounds__(256) void k_wpre(const h_t* __restrict__ Wqh,
                                              const h_t* __restrict__ Wkh,
                                              const h_t* __restrict__ Wot,
                                              const h_t* __restrict__ Wvh,
                                              h_t* __restrict__ Wkq,
                                              h_t* __restrict__ Wvot) {
    __shared__ h_t As[128 * 64];
    __shared__ h_t Bs[128 * 64];
    int t = threadIdx.x, w = t >> 6, lane = t & 63;
    int q16 = lane >> 4, l16 = lane & 15;
    int id = blockIdx.x;
    const h_t* A;
    const h_t* Bt;
    h_t* C;
    float oscale;
    if (id < 16) { A = Wkh; Bt = Wqh; C = Wkq; oscale = 1.44269504f; }
    else { id -= 16; A = Wot; Bt = Wvh; C = Wvot; oscale = 1.0f; }
    size_t m0 = (size_t)(id >> 2) * 128, n0 = (size_t)(id & 3) * 128;
    const int K = 1024, N = 512;
    int wr = (w >> 1) * 64, wc = (w & 1) * 64;
    f4 acc[4][4] = {};

    for (int k0 = 0; k0 < K; k0 += 64) {
#pragma unroll
        for (int j = 0; j < 4; j++) {
            int q = w * 4 + j;
            int row = q * 8 + (lane >> 3);
            int ks = (((lane & 7) ^ (row & 7)) << 3);
            gl2lds16(A + (m0 + row) * K + k0 + ks, &As[q * 512]);
            gl2lds16(Bt + (n0 + row) * K + k0 + ks, &Bs[q * 512]);
        }
        __syncthreads();
#pragma unroll
        for (int ks = 0; ks < 2; ks++) {
            h8 av[4], bv[4];
#pragma unroll
            for (int i = 0; i < 4; i++) {
                int row = wr + i * 16 + l16;
                int ch = ks * 4 + q16;
                av[i] = *(const h8*)&As[row * 64 + ((ch ^ (row & 7)) << 3)];
            }
#pragma unroll
            for (int j = 0; j < 4; j++) {
                int row = wc + j * 16 + l16;
                int ch = ks * 4 + q16;
                bv[j] = *(const h8*)&Bs[row * 64 + ((ch ^ (row & 7)) << 3)];
            }
#pragma unroll
            for (int i = 0; i < 4; i++)
#pragma unroll
                for (int j = 0; j < 4; j++)
                    acc[i][j] = MFMA16(av[i], bv[j], acc[i][j]);
        }
        __syncthreads();
    }
#pragma unroll
    for (int i = 0; i < 4; i++) {
        size_t r0 = m0 + wr + i * 16 + q16 * 4;
#pragma unroll
        for (int j = 0; j < 4; j++) {
            size_t c = n0 + wc + j * 16 + l16;
#pragma unroll
            for (int r = 0; r < 4; r++)
                C[(r0 + r) * N + c] = (h_t)(acc[i][j][r] * oscale);
        }
    }
}

// ---------------- fused T / V'' projections (1024 blocks), PIPELINED --------------
__global__ __launch_bounds__(256) void k_proj2(const h_t* __restrict__ S2h,
                                               const h_t* __restrict__ S1h,
                                               const h_t* __restrict__ Wkq,
                                               const h_t* __restrict__ Wvot,
                                               const float* __restrict__ bo,
                                               h_t* __restrict__ T,
                                               h_t* __restrict__ Vt) {
    __shared__ h_t smem[2][16384];  // 64 KB: buf[i] = As(8192 h) + Bs(8192 h)
    int t = threadIdx.x, w = t >> 6, lane = t & 63;
    int q16 = lane >> 4, l16 = lane & 15;
    int id = blockIdx.x;
    int mode = id >> 9;
    id &= 511;
    const h_t* A = mode ? S1h : S2h;
    const h_t* Bt = mode ? Wvot : Wkq;
    size_t m0 = (size_t)(id >> 2) * 128, n0 = (size_t)(id & 3) * 128;
    int wr = (w >> 1) * 64, wc = (w & 1) * 64;
    f4 acc[4][4] = {};

    auto STAGE = [&](int k0_, int bsel) {
#pragma unroll
        for (int j = 0; j < 4; j++) {
            int q = w * 4 + j;
            int row = q * 8 + (lane >> 3);
            int ks = (((lane & 7) ^ (row & 7)) << 3);
            gl2lds16(A + (m0 + row) * 512 + k0_ + ks, &smem[bsel][q * 512]);
            gl2lds16(Bt + (n0 + row) * 512 + k0_ + ks, &smem[bsel][8192 + q * 512]);
        }
    };

    STAGE(0, 0);
    int cur = 0;
#pragma unroll 1
    for (int it = 0; it < 8; it++) {
        if (it < 7) {
            STAGE((it + 1) * 64, cur ^ 1);
            asm volatile("s_waitcnt vmcnt(8)" ::: "memory");
        } else {
            asm volatile("s_waitcnt vmcnt(0)" ::: "memory");
        }
        __builtin_amdgcn_s_barrier();
        asm volatile("" ::: "memory");
        const h_t* As = &smem[cur][0];
        const h_t* Bs = &smem[cur][8192];
#pragma unroll
        for (int ks = 0; ks < 2; ks++) {
            h8 av[4], bv[4];
#pragma unroll
            for (int i = 0; i < 4; i++) {
                int row = wr + i * 16 + l16;
                int ch = ks * 4 + q16;
                av[i] = *(const h8*)&As[row * 64 + ((ch ^ (row & 7)) << 3)];
            }
#pragma unroll
            for (int j = 0; j < 4; j++) {
                int row = wc + j * 16 + l16;
                int ch = ks * 4 + q16;
                bv[j] = *(const h8*)&Bs[row * 64 + ((ch ^ (row & 7)) << 3)];
            }
#pragma unroll
            for (int i = 0; i < 4; i++)
#pragma unroll
                for (int j = 0; j < 4; j++)
                    acc[i][j] = MFMA16(av[i], bv[j], acc[i][j]);
        }
        asm volatile("" ::: "memory");
        __builtin_amdgcn_s_barrier();
        cur ^= 1;
    }
    if (mode == 0) {
#pragma unroll
        for (int i = 0; i < 4; i++) {
            size_t r0 = m0 + wr + i * 16 + q16 * 4;
#pragma unroll
            for (int j = 0; j < 4; j++) {
                size_t c = n0 + wc + j * 16 + l16;
#pragma unroll
                for (int r = 0; r < 4; r++)
                    T[(r0 + r) * 512 + c] = (h_t)acc[i][j][r];
            }
        }
    } else {
#pragma unroll
        for (int i = 0; i < 4; i++) {
            size_t gm = m0 + wr + i * 16 + q16 * 4;
            size_t b = gm >> 11;
            size_t n = gm & 2047;
#pragma unroll
            for (int j = 0; j < 4; j++) {
                size_t d = n0 + wc + j * 16 + l16;
                float bias = bo[d];
                h4 hv = {(h_t)(acc[i][j][0] + bias), (h_t)(acc[i][j][1] + bias),
                         (h_t)(acc[i][j][2] + bias), (h_t)(acc[i][j][3] + bias)};
                *(h4*)&Vt[(b * 512 + d) * 2048 + n] = hv;
            }
        }
    }
}

// ---------------- pass 1: 256x256 S^T-tile GEMM (K=512, PIPELINED) + stats + P ----
// grid (qt 8, kt 8, b 8) = 512 blocks, 512 thr (8 waves: wr=w>>2 key-group,
// wc=w&3 qrow-group). Swapped operands: keys = MFMA rows. BK=64 double-buffer,
// counted vmcnt(8). P-stage via dead GEMM buffers, two 128-row rounds.
__global__ __launch_bounds__(512, 2) void k_qk(const h_t* __restrict__ T,
                                               const h_t* __restrict__ S1h,
                                               h_t* __restrict__ P,
                                               float2* __restrict__ Mkt) {
    __shared__ h_t smem[2][32768];  // 128 KB: buf[i] = keys(16384 h) + qrows(16384 h)
    h_t* Ps = &smem[0][0];          // P-stage [128][264] h = 67584 B (aliases bufs)
    float* pmx = (float*)((char*)&smem[0][0] + 121856);  // [2][256] f32, 2 KB
    float* psm = (float*)((char*)&smem[0][0] + 123904);  // [2][256] f32, 2 KB
    int t = threadIdx.x, w = t >> 6, lane = t & 63;
    int q16 = lane >> 4, l16 = lane & 15;
    int wr = w >> 2, wc = w & 3;
    int qt = blockIdx.x, kt = blockIdx.y, b = blockIdx.z;
    const h_t* A = S1h + ((size_t)b * 2048 + kt * 256) * 512;   // keys
    const h_t* Bt = T + ((size_t)b * 2048 + qt * 256) * 512;    // qrows
    f4 acc[8][4] = {};

    auto STAGE = [&](int k0_, int bsel) {
#pragma unroll
        for (int j = 0; j < 4; j++) {
            int q = w * 4 + j;                 // 0..31
            int row = q * 8 + (lane >> 3);     // 0..255
            int ks = (((lane & 7) ^ (row & 7)) << 3);
            gl2lds16(A + (size_t)row * 512 + k0_ + ks, &smem[bsel][q * 512]);
            gl2lds16(Bt + (size_t)row * 512 + k0_ + ks, &smem[bsel][16384 + q * 512]);
        }
    };

    STAGE(0, 0);
    int cur = 0;
#pragma unroll 1
    for (int it = 0; it < 8; it++) {
        if (it < 7) {
            STAGE((it + 1) * 64, cur ^ 1);
            asm volatile("s_waitcnt vmcnt(8)" ::: "memory");
        } else {
            asm volatile("s_waitcnt vmcnt(0)" ::: "memory");
        }
        __builtin_amdgcn_s_barrier();
        asm volatile("" ::: "memory");
        const h_t* As = &smem[cur][0];
        const h_t* Bs = &smem[cur][16384];
#pragma unroll
        for (int ks = 0; ks < 2; ks++) {
            int ch = ks * 4 + q16;
            h8 av[8], bv[4];
#pragma unroll
            for (int i = 0; i < 8; i++) {
                int row = wr * 128 + i * 16 + l16;
                av[i] = *(const h8*)&As[row * 64 + ((ch ^ (row & 7)) << 3)];
            }
#pragma unroll
            for (int j = 0; j < 4; j++) {
                int row = wc * 64 + j * 16 + l16;
                bv[j] = *(const h8*)&Bs[row * 64 + ((ch ^ (row & 7)) << 3)];
            }
#pragma unroll
            for (int i = 0; i < 8; i++)
#pragma unroll
                for (int j = 0; j < 4; j++)
                    acc[i][j] = MFMA16(av[i], bv[j], acc[i][j]);
        }
        asm volatile("" ::: "memory");
        __builtin_amdgcn_s_barrier();
        cur ^= 1;
    }
    // acc[i][j][r]: key = wr*128 + i*16 + q16*4 + r, qrow = wc*64 + j*16 + l16.
    // ---- per-qrow stats: in-lane over (i,r), cross-lane over q16 only ----
    float lm[4], ls[4], sc[4];
#pragma unroll
    for (int j = 0; j < 4; j++) {
        float m = acc[0][j][0];
#pragma unroll
        for (int i = 0; i < 8; i++)
#pragma unroll
            for (int r = 0; r < 4; r++) m = fmaxf(m, acc[i][j][r]);
        lm[j] = m;
    }
#pragma unroll
    for (int msk = 16; msk <= 32; msk <<= 1)
#pragma unroll
        for (int j = 0; j < 4; j++)
            lm[j] = fmaxf(lm[j], __shfl_xor(lm[j], msk, 64));
#pragma unroll
    for (int j = 0; j < 4; j++) {
        float s = 0.f;
#pragma unroll
        for (int i = 0; i < 8; i++)
#pragma unroll
            for (int r = 0; r < 4; r++) {
                float e = exp2f(acc[i][j][r] - lm[j]);
                acc[i][j][r] = e;       // keep e; rescale by sc at P-write
                s += e;
            }
        ls[j] = s;
    }
#pragma unroll
    for (int msk = 16; msk <= 32; msk <<= 1)
#pragma unroll
        for (int j = 0; j < 4; j++) ls[j] += __shfl_xor(ls[j], msk, 64);
    if (q16 == 0) {
#pragma unroll
        for (int j = 0; j < 4; j++) {
            pmx[wr * 256 + wc * 64 + j * 16 + l16] = lm[j];
            psm[wr * 256 + wc * 64 + j * 16 + l16] = ls[j];
        }
    }
    __syncthreads();   // partials visible (all GEMM reads of smem also done)
    // ---- combine the two key-halves; sc = exp2(lm_wave - M_tile) ----
#pragma unroll
    for (int j = 0; j < 4; j++) {
        int row = wc * 64 + j * 16 + l16;
        float om = pmx[(wr ^ 1) * 256 + row];
        float os = psm[(wr ^ 1) * 256 + row];
        float M = fmaxf(lm[j], om);
        float s = exp2f(lm[j] - M);
        float L = ls[j] * s + os * exp2f(om - M);
        sc[j] = s;
        if (wr == 0 && q16 == 0)
            Mkt[((size_t)b * 8 + kt) * 2048 + qt * 256 + row] = make_float2(M, L);
    }
    // ---- P-stage in two 128-row rounds through the dead GEMM buffers ----
    size_t Pbase0 = ((size_t)b * 2048 + qt * 256) * 2048 + (size_t)kt * 256;
#pragma unroll
    for (int rnd = 0; rnd < 2; rnd++) {
        __syncthreads();               // prior round's Ps reads done
        if ((wc >> 1) == rnd) {
            int rloc = (wc & 1) * 64;  // local row base of this wave's qrows
#pragma unroll
            for (int j = 0; j < 4; j++)
#pragma unroll
                for (int i = 0; i < 8; i++) {
                    h4 hv = {(h_t)(acc[i][j][0] * sc[j]), (h_t)(acc[i][j][1] * sc[j]),
                             (h_t)(acc[i][j][2] * sc[j]), (h_t)(acc[i][j][3] * sc[j])};
                    *(h4*)&Ps[(rloc + j * 16 + l16) * 264 + wr * 128 + i * 16 + q16 * 4] = hv;
                }
        }
        __syncthreads();
        // cooperative coalesced store: 128 rows x 256 keys
        size_t Pbase = Pbase0 + (size_t)rnd * 128 * 2048;
#pragma unroll
        for (int p = 0; p < 8; p++) {
            int row = p * 16 + (t >> 5);
            int c8 = (t & 31) * 8;
            *(h8*)(P + Pbase + (size_t)row * 2048 + c8) = *(const h8*)&Ps[row * 264 + c8];
        }
    }
}

// ---------------- pass 2: O = sum_kt (P_kt * delta) @ V'', x 1/l_fin --------------
// grid (rt 16, dt 4, b 8) = 512 blocks, 256 thr, tile 128x128. PIPELINED:
// V double-buffered via gl2lds; P software-pipelined in registers (prA/prB).
// Stats prologue inlined (Mkt: 8 tiles of 256 keys).
__global__ __launch_bounds__(256) void k_pv(const h_t* __restrict__ P,
                                            const h_t* __restrict__ Vt,
                                            const float2* __restrict__ Mkt,
                                            float* __restrict__ Out) {
    __shared__ h_t As[128 * 64];    // P-tile 16 KB (delta-scaled), single
    __shared__ h_t Bs[2][128 * 64]; // V-tiles 2 x 16 KB
    __shared__ h_t dks[8][128];     // per-kt row deltas, 2 KB
    __shared__ float linv[128];     // 0.5 KB
    int t = threadIdx.x, w = t >> 6, lane = t & 63;
    int q16 = lane >> 4, l16 = lane & 15;
    int rt = blockIdx.x, dt = blockIdx.y, b = blockIdx.z;
    int rg = w >> 1, dg = w & 1;
    // ---- stats prologue: rows rt*128..+127 over 8 key-tiles ----
    if (t < 128) {
        float2 v[8];
        float m = -1e30f;
#pragma unroll
        for (int kt = 0; kt < 8; kt++) {
            v[kt] = Mkt[((size_t)b * 8 + kt) * 2048 + rt * 128 + t];
            m = fmaxf(m, v[kt].x);
        }
        float l = 0.f;
#pragma unroll
        for (int kt = 0; kt < 8; kt++) {
            float d = exp2f(v[kt].x - m);
            l += v[kt].y * d;
            dks[kt][t] = (h_t)d;
        }
        linv[t] = 1.f / l;
    }
    __syncthreads();

    const h_t* Pb = P + ((size_t)b * 2048 + rt * 128) * 2048;
    const h_t* Vb = Vt + ((size_t)b * 512 + dt * 128) * 2048;
    int srow = t >> 3, soct = t & 7;   // staging: row base / col octet
    f4 acc[4][4] = {};
    h8 prA[4], prB[4];

    auto VSTAGE = [&](int k0_, int bsel) {
#pragma unroll
        for (int j = 0; j < 4; j++) {
            int q = w * 4 + j;
            int row = q * 8 + (lane >> 3);
            int ks = (((lane & 7) ^ (row & 7)) << 3);
            gl2lds16(Vb + (size_t)row * 2048 + k0_ + ks, &Bs[bsel][q * 512]);
        }
    };
    auto ASTORE = [&](h8* pr, int kt_) {
#pragma unroll
        for (int p = 0; p < 4; p++) {
            int r_ = p * 32 + srow;
            h_t dh = dks[kt_][r_];
            h8 dv = {dh, dh, dh, dh, dh, dh, dh, dh};
            h8 v = pr[p] * dv;
            *(h8*)&As[r_ * 64 + ((soct ^ (r_ & 7)) << 3)] = v;
        }
    };
    auto MM = [&](const h_t* Bsc) {
#pragma unroll
        for (int ks = 0; ks < 2; ks++) {
            int ch = ks * 4 + q16;
            h8 av[4], bv[4];
#pragma unroll
            for (int i = 0; i < 4; i++) {
                int row = rg * 64 + i * 16 + l16;
                av[i] = *(const h8*)&As[row * 64 + ((ch ^ (row & 7)) << 3)];
            }
#pragma unroll
            for (int j = 0; j < 4; j++) {
                int dr = dg * 64 + j * 16 + l16;
                bv[j] = *(const h8*)&Bsc[dr * 64 + ((ch ^ (dr & 7)) << 3)];
            }
#pragma unroll
            for (int i = 0; i < 4; i++)
#pragma unroll
                for (int j = 0; j < 4; j++)
                    acc[i][j] = MFMA16(av[i], bv[j], acc[i][j]);
        }
    };

    // prologue: phase 0 P-regs + V-tile
#pragma unroll
    for (int p = 0; p < 4; p++)
        prA[p] = *(const h8*)(Pb + (size_t)(p * 32 + srow) * 2048 + soct * 8);
    VSTAGE(0, 0);

#pragma unroll 1
    for (int it2 = 0; it2 < 16; it2++) {
        int k0 = it2 * 128;
        // ---- even phase: buf0 / prA; prefetch k0+64 -> prB, buf1 ----
#pragma unroll
        for (int p = 0; p < 4; p++)
            prB[p] = *(const h8*)(Pb + (size_t)(p * 32 + srow) * 2048 + k0 + 64 + soct * 8);
        VSTAGE(k0 + 64, 1);
        asm volatile("s_waitcnt vmcnt(8)" ::: "memory");  // prA + V(buf0) ready
        ASTORE(prA, k0 >> 8);
        asm volatile("s_waitcnt lgkmcnt(0)" ::: "memory");
        __builtin_amdgcn_s_barrier();
        asm volatile("" ::: "memory");
        MM(&Bs[0][0]);
        asm volatile("" ::: "memory");
        __builtin_amdgcn_s_barrier();
        // ---- odd phase: buf1 / prB; prefetch k0+128 -> prA, buf0 ----
        if (it2 < 15) {
#pragma unroll
            for (int p = 0; p < 4; p++)
                prA[p] = *(const h8*)(Pb + (size_t)(p * 32 + srow) * 2048 + k0 + 128 + soct * 8);
            VSTAGE(k0 + 128, 0);
            asm volatile("s_waitcnt vmcnt(8)" ::: "memory");  // prB + V(buf1)
        } else {
            asm volatile("s_waitcnt vmcnt(0)" ::: "memory");
        }
        ASTORE(prB, (k0 + 64) >> 8);
        asm volatile("s_waitcnt lgkmcnt(0)" ::: "memory");
        __builtin_amdgcn_s_barrier();
        asm volatile("" ::: "memory");
        MM(&Bs[1][0]);
        asm volatile("" ::: "memory");
        __builtin_amdgcn_s_barrier();
    }
#pragma unroll
    for (int i = 0; i < 4; i++)
#pragma unroll
        for (int rr = 0; rr < 4; rr++) {
            int row = rg * 64 + i * 16 + q16 * 4 + rr;
            float lv = linv[row];
#pragma unroll
            for (int j = 0; j < 4; j++) {
                int d = dt * 128 + dg * 64 + j * 16 + l16;
                Out[((size_t)b * 2048 + rt * 128 + row) * 512 + d] =
                    acc[i][j][rr] * lv;
            }
        }
}

// ---------------- host ----------------
extern "C" void kernel_launch(void* const* d_in, const int* in_sizes, int n_in,
                              void* d_out, int out_size, void* d_ws, size_t ws_size,
                              hipStream_t stream) {
    const float* S1 = (const float*)d_in[0];
    const float* S2 = (const float*)d_in[1];
    const float* Wq = (const float*)d_in[2];
    const float* Wk = (const float*)d_in[3];
    const float* Wv = (const float*)d_in[4];
    const float* Wo = (const float*)d_in[5];
    const float* bo = (const float*)d_in[6];
    float* Out = (float*)d_out;

    char* ws = (char*)d_ws;
    // persistent through attention:
    h_t* S1h  = (h_t*)(ws);                  // 16 MB (live through k_qk)
    h_t* T    = (h_t*)(ws + 16777216);       // 16 MB (live through k_qk)
    h_t* Vt   = (h_t*)(ws + 33554432);       // 16 MB (live through k_pv)
    h_t* P    = (h_t*)(ws + 50331648);       // 64 MB [8][2048][2048]
    float2* Mkt = (float2*)(ws + 117440512); // 1 MB [8][8][2048]
    // aliases inside P (all dead before k_qk writes P):
    h_t* S2h  = (h_t*)(ws + 50331648);       // 16 MB (dead after k_proj2)
    h_t* Wqh  = (h_t*)(ws + 67108864);       // 1 MB
    h_t* Wkh  = (h_t*)(ws + 68157440);       // 1 MB
    h_t* Wvh  = (h_t*)(ws + 69206016);       // 1 MB
    h_t* Wot  = (h_t*)(ws + 70254592);       // 1 MB
    h_t* Wkq  = (h_t*)(ws + 71303168);       // 0.5 MB
    h_t* Wvot = (h_t*)(ws + 71827456);       // 0.5 MB

    k_prep<<<18432, 256, 0, stream>>>(S1, S2, Wq, Wk, Wv, Wo,
                                      S1h, S2h, Wqh, Wkh, Wvh, Wot);
    k_wpre<<<32, 256, 0, stream>>>(Wqh, Wkh, Wot, Wvh, Wkq, Wvot);
    k_proj2<<<1024, 256, 0, stream>>>(S2h, S1h, Wkq, Wvot, bo, T, Vt);
    k_qk<<<dim3(8, 8, 8), 512, 0, stream>>>(T, S1h, P, Mkt);
    k_pv<<<dim3(16, 4, 8), 256, 0, stream>>>(P, Vt, Mkt, Out);
}